// Round 4
// baseline (761.519 us; speedup 1.0000x reference)
//
#include <hip/hip_runtime.h>
#include <hip/hip_bf16.h>
#include <math.h>

#define PB 4
#define PN 8192
#define PD 1024
#define PH 16
#define PDH 64
#define PGH 256

typedef __bf16 bf16x8 __attribute__((ext_vector_type(8)));
typedef __bf16 bf16x2 __attribute__((ext_vector_type(2)));
typedef float f32x4 __attribute__((ext_vector_type(4)));
typedef unsigned int u32;
typedef unsigned short u16;

typedef __attribute__((address_space(3))) void lds_void_t;
typedef const __attribute__((address_space(1))) void gbl_void_t;
#define ASYNC_COPY16(gp, lp) \
    __builtin_amdgcn_global_load_lds((gbl_void_t*)(gp), (lds_void_t*)(lp), 16, 0, 0)

__device__ inline float gelu_exact(float x) {
    return 0.5f * x * (1.0f + erff(x * 0.70710678118654752440f));
}

__device__ inline float2 f2(float x, float y) { return make_float2(x, y); }
__device__ inline float2 cadd(float2 a, float2 b) { return f2(a.x + b.x, a.y + b.y); }
__device__ inline float2 csub(float2 a, float2 b) { return f2(a.x - b.x, a.y - b.y); }
__device__ inline float2 cmul(float2 a, float2 b) {
    return f2(a.x * b.x - a.y * b.y, a.x * b.y + a.y * b.x);
}

// XOR swizzle: uniform ~4-way (b64 floor) for every access pattern in the FFT
#define PHYS(i) ((i) ^ (((i) >> 4) & 15))

// pack two floats to bf16x2-in-u32 (low = first)
__device__ inline u32 packbf(float a, float b) {
    __bf16 ba = (__bf16)a, bb = (__bf16)b;
    return (u32)(*(u16*)&ba) | ((u32)(*(u16*)&bb) << 16);
}

// DIF radix-4 (radix-2^2: two radix-2 DIF layers, strides 2h then h)
__device__ inline void dif4(float2& a, float2& b, float2& c, float2& d,
                            float2 w2, float2 w1) {
    float2 A0 = cadd(a, c);
    float2 C0 = cmul(csub(a, c), w2);
    float2 B0 = cadd(b, d);
    float2 t  = cmul(csub(b, d), w2);
    float2 D0 = f2(t.y, -t.x);               // * (-i)
    a = cadd(A0, B0);
    b = cmul(csub(A0, B0), w1);
    c = cadd(C0, D0);
    d = cmul(csub(C0, D0), w1);
}

// DIT radix-4 (two radix-2 DIT layers, strides h then 2h)
__device__ inline void dit4(float2& a, float2& b, float2& c, float2& d,
                            float2 w2, float2 w1) {
    float2 tb = cmul(b, w1);
    float2 p0 = cadd(a, tb), p1 = csub(a, tb);
    float2 td = cmul(d, w1);
    float2 q0 = cadd(c, td), q1 = csub(c, td);
    float2 wq0 = cmul(q0, w2);
    float2 e   = cmul(q1, w2);
    float2 ei  = f2(-e.y, e.x);              // * (+i)
    a = cadd(p0, wq0);
    c = csub(p0, wq0);
    b = cadd(p1, ei);
    d = csub(p1, ei);
}

// forward radix-8 trip: layers {4h, 2h, h}, h = 2^S.
// X[c][b] at logical index base + c*4h + b*h, off = base mod h (= base mod 4h).
// Layer 4h: pairs (X[0][b], X[1][b]), twiddle cis(-2pi(off+b*h)/(8h)).
// Layers 2h,h: dif4 across b with w2 = t8^2 = cis(-2pi off/(4h)), w1 = w2^2.
template<int S>
__device__ inline void fwd8_layers(float2 X[2][4], int off) {
    const float ang = -6.283185307179586f / (float)(8 << S);
    float sn, cs;
    __sincosf(ang * (float)off, &sn, &cs);
    float2 t8 = f2(cs, sn);
    const float2 c4m = f2(0.70710678118654752f, -0.70710678118654752f); // cis(-pi/4)
    float2 T = t8;
    #pragma unroll
    for (int b = 0; b < 4; b++) {
        float2 u = X[0][b], v = X[1][b];
        X[0][b] = cadd(u, v);
        X[1][b] = cmul(csub(u, v), T);
        T = cmul(T, c4m);
    }
    float2 w2 = cmul(t8, t8);
    float2 w1 = cmul(w2, w2);
    #pragma unroll
    for (int c = 0; c < 2; c++)
        dif4(X[c][0], X[c][1], X[c][2], X[c][3], w2, w1);
}

// inverse radix-8 trip: layers {h, 2h, 4h}, h = 2^S.
// Layers h,2h: dit4 across b with w2 = t8^2, w1 = w2^2.
// Layer 4h: pairs (X[0][b], X[1][b]), twiddle cis(+2pi(off+b*h)/(8h)).
template<int S>
__device__ inline void inv8_layers(float2 X[2][4], int off) {
    const float ang = 6.283185307179586f / (float)(8 << S);
    float sn, cs;
    __sincosf(ang * (float)off, &sn, &cs);
    float2 t8 = f2(cs, sn);
    float2 w2 = cmul(t8, t8);
    float2 w1 = cmul(w2, w2);
    #pragma unroll
    for (int c = 0; c < 2; c++)
        dit4(X[c][0], X[c][1], X[c][2], X[c][3], w2, w1);
    const float2 c4p = f2(0.70710678118654752f, 0.70710678118654752f);  // cis(+pi/4)
    float2 T = t8;
    #pragma unroll
    for (int b = 0; b < 4; b++) {
        float2 tb = cmul(X[1][b], T);
        float2 u = X[0][b];
        X[0][b] = cadd(u, tb);
        X[1][b] = csub(u, tb);
        T = cmul(T, c4p);
    }
}

// stride-1 radix-2 via lane exchange (pair partner = lane^1), 8-element tile
__device__ inline void r2_shfl8(float2 X[2][4], bool ev) {
    #pragma unroll
    for (int c = 0; c < 2; c++)
        #pragma unroll
        for (int b = 0; b < 4; b++) {
            float2 o = f2(__shfl_xor(X[c][b].x, 1, 64), __shfl_xor(X[c][b].y, 1, 64));
            X[c][b] = ev ? cadd(X[c][b], o) : csub(o, X[c][b]);
        }
}

// ---------------------------- fused convert x->bf16 + xsum[b,d] = sum_n x (one pass)
__global__ void convert_reduce(const float* __restrict__ x, __bf16* __restrict__ xb,
                               float* __restrict__ xsum) {
    int b = blockIdx.z;
    int d = blockIdx.y * 256 + threadIdx.x;
    int n0 = blockIdx.x * 256;
    const float* p = x + ((size_t)b * PN + n0) * PD + d;
    __bf16* q = xb + ((size_t)b * PN + n0) * PD + d;
    float s = 0.0f;
    #pragma unroll 4
    for (int i = 0; i < 256; i++) {
        float v = p[(size_t)i * PD];
        s += v;
        q[(size_t)i * PD] = (__bf16)v;
    }
    atomicAdd(&xsum[b * PD + d], s);
}

// ------------------------- transpose+convert w_v, w_o -> bf16 N x K (LDS 64x64 tiles)
__global__ void transpose_w(const float* __restrict__ wv, const float* __restrict__ wo,
                            __bf16* __restrict__ wvt, __bf16* __restrict__ wot) {
    __shared__ float t[64][65];
    const float* src = blockIdx.z ? wo : wv;
    __bf16* dst = blockIdx.z ? wot : wvt;
    int r0 = blockIdx.y * 64, c0 = blockIdx.x * 64;
    int lr = threadIdx.x >> 6, lc = threadIdx.x & 63;
    #pragma unroll
    for (int i = 0; i < 16; i++)
        t[lr + 4 * i][lc] = src[(size_t)(r0 + lr + 4 * i) * PD + c0 + lc];
    __syncthreads();
    #pragma unroll
    for (int i = 0; i < 16; i++)
        dst[(size_t)(c0 + lr + 4 * i) * PD + r0 + lc] = (__bf16)t[lc][lr + 4 * i];
}

// --------------------------------- bar_q = (xsum/N) @ w_q, then LayerNorm over DH=64
// split-K: 4 waves each dot 256 k's for the same 64 cols; wave 0 combines + LN
__global__ void barq_ln(const float* __restrict__ xsum, const float* __restrict__ w_q,
                        const float* __restrict__ ln_g, const float* __restrict__ ln_b,
                        float* __restrict__ bar_ln) {
    int b = blockIdx.y;
    int lane = threadIdx.x & 63;
    int w = threadIdx.x >> 6;
    int c = blockIdx.x * 64 + lane;
    const float* xs = xsum + b * PD + w * 256;
    const float* wq = w_q + (size_t)(w * 256) * PD + c;
    float acc = 0.0f;
    for (int k = 0; k < 256; k++) acc += xs[k] * wq[(size_t)k * PD];
    __shared__ float part[4][64];
    part[w][lane] = acc;
    __syncthreads();
    if (w == 0) {
        float bar = (part[0][lane] + part[1][lane] + part[2][lane] + part[3][lane])
                    * (1.0f / (float)PN);
        float mu = bar;
        for (int o = 32; o > 0; o >>= 1) mu += __shfl_xor(mu, o, 64);
        mu *= (1.0f / 64.0f);
        float d0 = bar - mu;
        float vv = d0 * d0;
        for (int o = 32; o > 0; o >>= 1) vv += __shfl_xor(vv, o, 64);
        vv *= (1.0f / 64.0f);
        bar_ln[b * PD + c] = d0 * rsqrtf(vv + 1e-5f) * ln_g[lane] + ln_b[lane];
    }
}

// ---------------------------- t_gate = gelu(bar@gate_w1); t_wrm = gelu(bar@wrm_w1)
__global__ void small1(const float* __restrict__ bar_ln, const float* __restrict__ gw1,
                       const float* __restrict__ ww1, float* __restrict__ tg,
                       float* __restrict__ tw) {
    int bh = blockIdx.x;
    int j = threadIdx.x;
    __shared__ float bl[PDH];
    if (j < PDH) bl[j] = bar_ln[bh * PDH + j];
    __syncthreads();
    float a1 = 0.0f, a2 = 0.0f;
    for (int k = 0; k < PDH; k++) {
        float bv = bl[k];
        a1 += bv * gw1[k * PGH + j];
        a2 += bv * ww1[k * PGH + j];
    }
    tg[bh * PGH + j] = gelu_exact(a1);
    tw[bh * PGH + j] = gelu_exact(a2);
}

// ---------------------- g_raw = t_gate@gate_w2 (64x16384); s = t_wrm@wrm_w2 (64x8192)
__global__ void small2(const float* __restrict__ tg, const float* __restrict__ tw,
                       const float* __restrict__ gw2, const float* __restrict__ ww2,
                       float* __restrict__ g_raw, float* __restrict__ s_full) {
    int chunk = blockIdx.x;
    int bh0 = blockIdx.y * 8;
    bool isg = chunk < 64;
    const float* t = isg ? tg : tw;
    const float* w2 = isg ? gw2 : ww2;
    int stride = isg ? (2 * PN) : PN;
    int col = (isg ? chunk : chunk - 64) * 256 + threadIdx.x;
    __shared__ float tl[8][PGH];
    #pragma unroll
    for (int i = 0; i < 8; i++) tl[i][threadIdx.x] = t[(bh0 + i) * PGH + threadIdx.x];
    __syncthreads();
    float acc[8] = {0, 0, 0, 0, 0, 0, 0, 0};
    for (int k = 0; k < PGH; k++) {
        float w = w2[(size_t)k * stride + col];
        #pragma unroll
        for (int i = 0; i < 8; i++) acc[i] += tl[i][k] * w;
    }
    #pragma unroll
    for (int i = 0; i < 8; i++) {
        if (isg) g_raw[(size_t)(bh0 + i) * (2 * PN) + col] = acc[i];
        else     s_full[(size_t)(bh0 + i) * PN + col] = acc[i];
    }
}

// --------------------------------------------- GEMM1: C = A * Bt^T, pair-layout output
__global__ __launch_bounds__(256) void gemm_pair(const __bf16* __restrict__ A,
                                                 const __bf16* __restrict__ Bt,
                                                 u32* __restrict__ vt) {
    constexpr int K = PD, LDK = 32;
    __shared__ __attribute__((aligned(16))) __bf16 As[128 * LDK];
    __shared__ __attribute__((aligned(16))) __bf16 Bs[128 * LDK];
    const int tid = threadIdx.x;
    const int lane = tid & 63;
    const int wave = tid >> 6;
    const int wm = (wave >> 1) << 6;
    const int wn = (wave & 1) << 6;
    const int tileM = blockIdx.y << 7;
    const int tileN = blockIdx.x << 7;
    const int r = tid >> 2;
    const int cg = tid & 3;
    const int mrow = lane & 15;
    const int k0 = (lane >> 4) << 3;

    f32x4 acc[4][4] = {};
    const __bf16* Aptr = A + (size_t)(tileM + r) * K + cg * 8;
    const __bf16* Bptr = Bt + (size_t)(tileN + r) * K + cg * 8;

    for (int kt = 0; kt < K; kt += 32) {
        __syncthreads();
        ASYNC_COPY16(Aptr + kt,                  As + tid * 8);
        ASYNC_COPY16(Aptr + (size_t)64 * K + kt, As + 64 * LDK + tid * 8);
        ASYNC_COPY16(Bptr + kt,                  Bs + tid * 8);
        ASYNC_COPY16(Bptr + (size_t)64 * K + kt, Bs + 64 * LDK + tid * 8);
        __syncthreads();
        bf16x8 af[4], bfr[4];
        #pragma unroll
        for (int i = 0; i < 4; i++) af[i]  = *(const bf16x8*)&As[(wm + i * 16 + mrow) * LDK + k0];
        #pragma unroll
        for (int j = 0; j < 4; j++) bfr[j] = *(const bf16x8*)&Bs[(wn + j * 16 + mrow) * LDK + k0];
        #pragma unroll
        for (int i = 0; i < 4; i++)
            #pragma unroll
            for (int j = 0; j < 4; j++)
                acc[i][j] = __builtin_amdgcn_mfma_f32_16x16x32_bf16(af[i], bfr[j], acc[i][j], 0, 0, 0);
    }

    const int rq = (lane >> 4) << 2;
    const bool evl = (lane & 1) == 0;
    #pragma unroll
    for (int i = 0; i < 4; i++) {
        int grow = tileM + wm + i * 16 + rq;
        int b = grow >> 13;
        int nb = grow & 8191;
        #pragma unroll
        for (int j = 0; j < 4; j++) {
            u32 w[4];
            #pragma unroll
            for (int rr = 0; rr < 4; rr++) {
                float a = acc[i][j][rr];
                float o = __shfl_xor(a, 1, 64);
                w[rr] = packbf(a, o);
            }
            if (evl) {
                int col = tileN + wn + j * 16 + mrow;
                size_t idx = ((size_t)b * 512 + (col >> 1)) * PN + nb;
                *(uint4*)(vt + idx) = make_uint4(w[0], w[1], w[2], w[3]);
            }
        }
    }
}

// ----------------------------- GEMM2: C = Y * Bt^T with Y given in pair layout (=Y^T)
__global__ __launch_bounds__(256) void gemm_ta(const u32* __restrict__ yt,
                                               const __bf16* __restrict__ Bt,
                                               float* __restrict__ Cf) {
    constexpr int K = PD, Nc = PD, LDKA = 40, LDKB = 32;
    __shared__ __attribute__((aligned(16))) __bf16 As[128 * LDKA];
    __shared__ __attribute__((aligned(16))) __bf16 Bs[128 * LDKB];
    u32* As32 = (u32*)As;
    const int tid = threadIdx.x;
    const int lane = tid & 63;
    const int wave = tid >> 6;
    const int wm = (wave >> 1) << 6;
    const int wn = (wave & 1) << 6;
    const int tileM = blockIdx.y << 7;
    const int tileN = blockIdx.x << 7;
    const int r = tid >> 2;
    const int cg = tid & 3;
    const int mrow = lane & 15;
    const int k0 = (lane >> 4) << 3;
    const int prow = tid & 7;
    const int seg = tid >> 3;

    const int b = tileM >> 13;
    const int n0 = tileM & 8191;
    const u32* abase = yt + ((size_t)b * 512 + prow) * PN + n0 + seg * 4;
    const __bf16* Bptr = Bt + (size_t)(tileN + r) * K + cg * 8;

    f32x4 acc[4][4] = {};
    uint4 pa0 = *(const uint4*)(abase);
    uint4 pa1 = *(const uint4*)(abase + (size_t)8 * PN);

    for (int kt = 0; kt < K; kt += 32) {
        __syncthreads();
        {
            int m0 = seg * 4;
            As32[(m0 + 0) * 20 + prow] = pa0.x;
            As32[(m0 + 1) * 20 + prow] = pa0.y;
            As32[(m0 + 2) * 20 + prow] = pa0.z;
            As32[(m0 + 3) * 20 + prow] = pa0.w;
            As32[(m0 + 0) * 20 + prow + 8] = pa1.x;
            As32[(m0 + 1) * 20 + prow + 8] = pa1.y;
            As32[(m0 + 2) * 20 + prow + 8] = pa1.z;
            As32[(m0 + 3) * 20 + prow + 8] = pa1.w;
        }
        ASYNC_COPY16(Bptr + kt,                  Bs + tid * 8);
        ASYNC_COPY16(Bptr + (size_t)64 * K + kt, Bs + 64 * LDKB + tid * 8);
        if (kt + 32 < K) {
            const u32* nxt = abase + (size_t)((kt >> 1) + 16) * PN;
            pa0 = *(const uint4*)(nxt);
            pa1 = *(const uint4*)(nxt + (size_t)8 * PN);
        }
        __syncthreads();
        bf16x8 af[4], bfr[4];
        #pragma unroll
        for (int i = 0; i < 4; i++) af[i]  = *(const bf16x8*)&As[(wm + i * 16 + mrow) * LDKA + k0];
        #pragma unroll
        for (int j = 0; j < 4; j++) bfr[j] = *(const bf16x8*)&Bs[(wn + j * 16 + mrow) * LDKB + k0];
        #pragma unroll
        for (int i = 0; i < 4; i++)
            #pragma unroll
            for (int j = 0; j < 4; j++)
                acc[i][j] = __builtin_amdgcn_mfma_f32_16x16x32_bf16(af[i], bfr[j], acc[i][j], 0, 0, 0);
    }

    const int rq = (lane >> 4) << 2;
    #pragma unroll
    for (int i = 0; i < 4; i++) {
        #pragma unroll
        for (int rr = 0; rr < 4; rr++) {
            int row = tileM + wm + i * 16 + rq + rr;
            size_t base = (size_t)row * Nc + tileN + wn + mrow;
            #pragma unroll
            for (int j = 0; j < 4; j++) Cf[base + j * 16] = acc[i][j][rr];
        }
    }
}

// ------------------------------------------------- FFT conv + hadamard/scale epilogue
// 1024 threads, 8 elems/thread, radix-8 per LDS round trip. 9 barriers.
// VGPR target <=64 so 2 blocks/CU (32 waves/CU) co-reside with 2x64KB LDS.
__global__ __launch_bounds__(1024, 8) void fftconv(const u32* __restrict__ vt,
                                                   const float* __restrict__ g_raw,
                                                   const float* __restrict__ s_full,
                                                   u32* __restrict__ yt) {
    __shared__ float2 Z[PN];   // 64 KB
    const int tid = threadIdx.x;           // 0..1023
    const int row = blockIdx.x;            // b*512 + pair
    const int bh = row >> 5;
    const u32* vp = vt + (size_t)row * PN;
    const bool ev = (tid & 1) == 0;

    // ---- P1: global gather -> fwd layers 4096,2048,1024 -> LDS
    {
        float2 X[2][4];
        #pragma unroll
        for (int c = 0; c < 2; c++)
            #pragma unroll
            for (int b = 0; b < 4; b++) {
                u32 pw = vp[tid + c * 4096 + b * 1024];
                bf16x2 pp = *(bf16x2*)&pw;
                X[c][b] = f2((float)pp.x, (float)pp.y);
            }
        fwd8_layers<10>(X, tid);
        #pragma unroll
        for (int c = 0; c < 2; c++)
            #pragma unroll
            for (int b = 0; b < 4; b++)
                Z[PHYS(tid + c * 4096 + b * 1024)] = X[c][b];
    }
    __syncthreads();

    // ---- P2: fwd layers 512,256,128
    {
        const int base = ((tid >> 7) << 10) + (tid & 127);
        float2 X[2][4];
        #pragma unroll
        for (int c = 0; c < 2; c++)
            #pragma unroll
            for (int b = 0; b < 4; b++)
                X[c][b] = Z[PHYS(base + c * 512 + b * 128)];
        fwd8_layers<7>(X, tid & 127);
        #pragma unroll
        for (int c = 0; c < 2; c++)
            #pragma unroll
            for (int b = 0; b < 4; b++)
                Z[PHYS(base + c * 512 + b * 128)] = X[c][b];
    }
    __syncthreads();

    // ---- P3: fwd layers 64,32,16
    {
        const int base = ((tid >> 4) << 7) + (tid & 15);
        float2 X[2][4];
        #pragma unroll
        for (int c = 0; c < 2; c++)
            #pragma unroll
            for (int b = 0; b < 4; b++)
                X[c][b] = Z[PHYS(base + c * 64 + b * 16)];
        fwd8_layers<4>(X, tid & 15);
        #pragma unroll
        for (int c = 0; c < 2; c++)
            #pragma unroll
            for (int b = 0; b < 4; b++)
                Z[PHYS(base + c * 64 + b * 16)] = X[c][b];
    }
    __syncthreads();

    // ---- P4: fwd layers 8,4,2 + stride-1 radix-2 via shfl
    {
        const int base = ((tid >> 1) << 4) + (tid & 1);
        float2 X[2][4];
        #pragma unroll
        for (int c = 0; c < 2; c++)
            #pragma unroll
            for (int b = 0; b < 4; b++)
                X[c][b] = Z[PHYS(base + c * 8 + b * 2)];
        fwd8_layers<1>(X, tid & 1);
        r2_shfl8(X, ev);
        #pragma unroll
        for (int c = 0; c < 2; c++)
            #pragma unroll
            for (int b = 0; b < 4; b++)
                Z[PHYS(base + c * 8 + b * 2)] = X[c][b];
    }
    __syncthreads();

    // ---- spectral stage in bitrev addressing
    {
        const float* gr = g_raw + (size_t)bh * (2 * PN);
        const float* gi = gr + PN;
        for (int m = tid; m < PN / 2 + 1; m += 1024) {
            int p  = (m < PN / 2) ? 2 * m : 1;
            int k  = __brev((unsigned)p) >> 19;
            int Nk = (PN - k) & (PN - 1);
            int qd = __brev((unsigned)Nk) >> 19;
            float2 Za = Z[PHYS(p)], Zb = Z[PHYS(qd)];
            float v1r = 0.5f * (Za.x + Zb.x), v1i = 0.5f * (Za.y - Zb.y);
            float v2r = 0.5f * (Za.y + Zb.y), v2i = 0.5f * (Zb.x - Za.x);
            float grk = gr[k],  gik = gi[k];
            float grn = gr[Nk], gin = gi[Nk];
            float y1r  = v1r * grk - v1i * gik, y1i  = v1r * gik + v1i * grk;
            float y2r  = v2r * grk - v2i * gik, y2i  = v2r * gik + v2i * grk;
            float y1nr = v1r * grn + v1i * gin, y1ni = v1r * gin - v1i * grn;
            float y2nr = v2r * grn + v2i * gin, y2ni = v2r * gin - v2i * grn;
            float ys1r = 0.5f * (y1r + y1nr), ys1i = 0.5f * (y1i - y1ni);
            float ys2r = 0.5f * (y2r + y2nr), ys2i = 0.5f * (y2i - y2ni);
            Z[PHYS(p)] = f2(ys1r - ys2i, ys1i + ys2r);
            if (qd != p) Z[PHYS(qd)] = f2(ys1r + ys2i, ys2r - ys1i);
        }
    }
    __syncthreads();

    // ---- P5: stride-1 radix-2 via shfl + inv layers 2,4,8
    {
        const int base = ((tid >> 1) << 4) + (tid & 1);
        float2 X[2][4];
        #pragma unroll
        for (int c = 0; c < 2; c++)
            #pragma unroll
            for (int b = 0; b < 4; b++)
                X[c][b] = Z[PHYS(base + c * 8 + b * 2)];
        r2_shfl8(X, ev);
        inv8_layers<1>(X, tid & 1);
        #pragma unroll
        for (int c = 0; c < 2; c++)
            #pragma unroll
            for (int b = 0; b < 4; b++)
                Z[PHYS(base + c * 8 + b * 2)] = X[c][b];
    }
    __syncthreads();

    // ---- P6: inv layers 16,32,64
    {
        const int base = ((tid >> 4) << 7) + (tid & 15);
        float2 X[2][4];
        #pragma unroll
        for (int c = 0; c < 2; c++)
            #pragma unroll
            for (int b = 0; b < 4; b++)
                X[c][b] = Z[PHYS(base + c * 64 + b * 16)];
        inv8_layers<4>(X, tid & 15);
        #pragma unroll
        for (int c = 0; c < 2; c++)
            #pragma unroll
            for (int b = 0; b < 4; b++)
                Z[PHYS(base + c * 64 + b * 16)] = X[c][b];
    }
    __syncthreads();

    // ---- P7: inv layers 128,256,512
    {
        const int base = ((tid >> 7) << 10) + (tid & 127);
        float2 X[2][4];
        #pragma unroll
        for (int c = 0; c < 2; c++)
            #pragma unroll
            for (int b = 0; b < 4; b++)
                X[c][b] = Z[PHYS(base + c * 512 + b * 128)];
        inv8_layers<7>(X, tid & 127);
        #pragma unroll
        for (int c = 0; c < 2; c++)
            #pragma unroll
            for (int b = 0; b < 4; b++)
                Z[PHYS(base + c * 512 + b * 128)] = X[c][b];
    }
    __syncthreads();

    // ---- P8: inv layers 1024,2048,4096
    {
        float2 X[2][4];
        #pragma unroll
        for (int c = 0; c < 2; c++)
            #pragma unroll
            for (int b = 0; b < 4; b++)
                X[c][b] = Z[PHYS(tid + c * 4096 + b * 1024)];
        inv8_layers<10>(X, tid);
        #pragma unroll
        for (int c = 0; c < 2; c++)
            #pragma unroll
            for (int b = 0; b < 4; b++)
                Z[PHYS(tid + c * 4096 + b * 1024)] = X[c][b];
    }
    __syncthreads();

    // ---- epilogue: v_tilde + second-butterfly(s * first-butterfly(v_tilde))
    // Z fully inverse-transformed (natural order, unnormalized).
    {
        const float* sp = s_full + (size_t)bh * PN;
        u32* yp = yt + (size_t)row * PN;
        const float inv = 1.0f / (float)PN;
        const float I2 = 0.70710678118654752440f;
        const int nb = tid;            // 0..1023
        const int n0 = nb * 8;
        const int np0 = nb * 4;
        u32 ou[8];
        #pragma unroll
        for (int pp = 0; pp < 4; pp++) {
            float2 z0 = Z[PHYS(n0 + 2 * pp)];
            float2 z1 = Z[PHYS(n0 + 2 * pp + 1)];
            float s0  = sp[np0 + pp];
            float s1v = sp[np0 + pp + PN / 2];
            float ax = z0.x * inv, ay = z0.y * inv;
            float bx = z1.x * inv, by = z1.y * inv;
            float wlx = (ax + bx) * I2 * s0, whx = (ax - bx) * I2 * s1v;
            float evx = (wlx + whx) * I2,   odx = (wlx - whx) * I2;
            float wly = (ay + by) * I2 * s0, why = (ay - by) * I2 * s1v;
            float evy = (wly + why) * I2,   ody = (wly - why) * I2;
            ou[2 * pp]     = packbf(ax + evx, ay + evy);
            ou[2 * pp + 1] = packbf(bx + odx, by + ody);
        }
        *(uint4*)(yp + n0)     = make_uint4(ou[0], ou[1], ou[2], ou[3]);
        *(uint4*)(yp + n0 + 4) = make_uint4(ou[4], ou[5], ou[6], ou[7]);
    }
}

// ================================================================ launcher
extern "C" void kernel_launch(void* const* d_in, const int* in_sizes, int n_in,
                              void* d_out, int out_size, void* d_ws, size_t ws_size,
                              hipStream_t stream) {
    const float* x    = (const float*)d_in[0];
    const float* w_q  = (const float*)d_in[1];
    const float* w_v  = (const float*)d_in[2];
    const float* w_o  = (const float*)d_in[3];
    const float* ln_g = (const float*)d_in[4];
    const float* ln_b = (const float*)d_in[5];
    const float* gw1  = (const float*)d_in[6];
    const float* gw2  = (const float*)d_in[7];
    const float* ww1  = (const float*)d_in[8];
    const float* ww2  = (const float*)d_in[9];
    float* out = (float*)d_out;

    const size_t XE = (size_t)PB * PN * PD;        // 33554432
    __bf16* xb   = (__bf16*)d_ws;                  // x bf16; later reused: fft out (pair)
    __bf16* vb   = xb + XE;                        // gemm1 out (pair layout)
    __bf16* wvt  = vb + XE;
    __bf16* wot  = wvt + (size_t)PD * PD;
    float*  xsum = (float*)(wot + (size_t)PD * PD);
    float*  bar  = xsum + PB * PD;
    float*  tg   = bar + PB * PD;
    float*  tw   = tg + 64 * PGH;
    float*  graw = tw + 64 * PGH;
    float*  sful = graw + (size_t)64 * 2 * PN;

    hipMemsetAsync(xsum, 0, PB * PD * sizeof(float), stream);

    convert_reduce<<<dim3(PN / 256, PD / 256, PB), 256, 0, stream>>>(x, xb, xsum);
    transpose_w<<<dim3(16, 16, 2), 256, 0, stream>>>(w_v, w_o, wvt, wot);
    barq_ln<<<dim3(PD / 64, PB), 256, 0, stream>>>(xsum, w_q, ln_g, ln_b, bar);
    small1<<<PB * PH, 256, 0, stream>>>(bar, gw1, ww1, tg, tw);
    small2<<<dim3(96, 8), 256, 0, stream>>>(tg, tw, gw2, ww2, graw, sful);
    // v = x @ w_v, written directly in pair-transposed layout
    gemm_pair<<<dim3(PD / 128, PB * PN / 128), 256, 0, stream>>>(xb, wvt, (u32*)vb);
    // FFT conv: vb (pair) -> xb (pair)
    fftconv<<<PB * 512, 1024, 0, stream>>>((const u32*)vb, graw, sful, (u32*)xb);
    // out = y @ w_o, A staged from pair layout
    gemm_ta<<<dim3(PD / 128, PB * PN / 128), 256, 0, stream>>>((const u32*)xb, wot, out);
}

// Round 5
// 725.982 us; speedup vs baseline: 1.0490x; 1.0490x over previous
//
#include <hip/hip_runtime.h>
#include <hip/hip_bf16.h>
#include <math.h>

#define PB 4
#define PN 8192
#define PD 1024
#define PH 16
#define PDH 64
#define PGH 256

typedef __bf16 bf16x8 __attribute__((ext_vector_type(8)));
typedef __bf16 bf16x2 __attribute__((ext_vector_type(2)));
typedef float f32x4 __attribute__((ext_vector_type(4)));
typedef unsigned int u32;
typedef unsigned short u16;

typedef __attribute__((address_space(3))) void lds_void_t;
typedef const __attribute__((address_space(1))) void gbl_void_t;
#define ASYNC_COPY16(gp, lp) \
    __builtin_amdgcn_global_load_lds((gbl_void_t*)(gp), (lds_void_t*)(lp), 16, 0, 0)

__device__ inline float gelu_exact(float x) {
    return 0.5f * x * (1.0f + erff(x * 0.70710678118654752440f));
}

__device__ inline float2 f2(float x, float y) { return make_float2(x, y); }
__device__ inline float2 cadd(float2 a, float2 b) { return f2(a.x + b.x, a.y + b.y); }
__device__ inline float2 csub(float2 a, float2 b) { return f2(a.x - b.x, a.y - b.y); }
__device__ inline float2 cmul(float2 a, float2 b) {
    return f2(a.x * b.x - a.y * b.y, a.x * b.y + a.y * b.x);
}

// XOR swizzle: uniform ~4-way (b64 floor) for every access pattern in the FFT
#define PHYS(i) ((i) ^ (((i) >> 4) & 15))

// pack two floats to bf16x2-in-u32 (low = first)
__device__ inline u32 packbf(float a, float b) {
    __bf16 ba = (__bf16)a, bb = (__bf16)b;
    return (u32)(*(u16*)&ba) | ((u32)(*(u16*)&bb) << 16);
}

// DIF radix-4 (radix-2^2: two radix-2 DIF layers, strides 2h then h)
__device__ inline void dif4(float2& a, float2& b, float2& c, float2& d,
                            float2 w2, float2 w1) {
    float2 A0 = cadd(a, c);
    float2 C0 = cmul(csub(a, c), w2);
    float2 B0 = cadd(b, d);
    float2 t  = cmul(csub(b, d), w2);
    float2 D0 = f2(t.y, -t.x);               // * (-i)
    a = cadd(A0, B0);
    b = cmul(csub(A0, B0), w1);
    c = cadd(C0, D0);
    d = cmul(csub(C0, D0), w1);
}

// DIT radix-4 (two radix-2 DIT layers, strides h then 2h)
__device__ inline void dit4(float2& a, float2& b, float2& c, float2& d,
                            float2 w2, float2 w1) {
    float2 tb = cmul(b, w1);
    float2 p0 = cadd(a, tb), p1 = csub(a, tb);
    float2 td = cmul(d, w1);
    float2 q0 = cadd(c, td), q1 = csub(c, td);
    float2 wq0 = cmul(q0, w2);
    float2 e   = cmul(q1, w2);
    float2 ei  = f2(-e.y, e.x);              // * (+i)
    a = cadd(p0, wq0);
    c = csub(p0, wq0);
    b = cadd(p1, ei);
    d = csub(p1, ei);
}

// forward radix-8 trip: layers {4h, 2h, h}, h = 2^S.
// X[c][b] at logical index base + c*4h + b*h, off = base mod h (= base mod 4h).
// Layer 4h: pairs (X[0][b], X[1][b]), twiddle cis(-2pi(off+b*h)/(8h)).
// Layers 2h,h: dif4 across b with w2 = t8^2 = cis(-2pi off/(4h)), w1 = w2^2.
template<int S>
__device__ inline void fwd8_layers(float2 X[2][4], int off) {
    const float ang = -6.283185307179586f / (float)(8 << S);
    float sn, cs;
    __sincosf(ang * (float)off, &sn, &cs);
    float2 t8 = f2(cs, sn);
    const float2 c4m = f2(0.70710678118654752f, -0.70710678118654752f); // cis(-pi/4)
    float2 T = t8;
    #pragma unroll
    for (int b = 0; b < 4; b++) {
        float2 u = X[0][b], v = X[1][b];
        X[0][b] = cadd(u, v);
        X[1][b] = cmul(csub(u, v), T);
        T = cmul(T, c4m);
    }
    float2 w2 = cmul(t8, t8);
    float2 w1 = cmul(w2, w2);
    #pragma unroll
    for (int c = 0; c < 2; c++)
        dif4(X[c][0], X[c][1], X[c][2], X[c][3], w2, w1);
}

// inverse radix-8 trip: layers {h, 2h, 4h}, h = 2^S.
// Layers h,2h: dit4 across b with w2 = t8^2, w1 = w2^2.
// Layer 4h: pairs (X[0][b], X[1][b]), twiddle cis(+2pi(off+b*h)/(8h)).
template<int S>
__device__ inline void inv8_layers(float2 X[2][4], int off) {
    const float ang = 6.283185307179586f / (float)(8 << S);
    float sn, cs;
    __sincosf(ang * (float)off, &sn, &cs);
    float2 t8 = f2(cs, sn);
    float2 w2 = cmul(t8, t8);
    float2 w1 = cmul(w2, w2);
    #pragma unroll
    for (int c = 0; c < 2; c++)
        dit4(X[c][0], X[c][1], X[c][2], X[c][3], w2, w1);
    const float2 c4p = f2(0.70710678118654752f, 0.70710678118654752f);  // cis(+pi/4)
    float2 T = t8;
    #pragma unroll
    for (int b = 0; b < 4; b++) {
        float2 tb = cmul(X[1][b], T);
        float2 u = X[0][b];
        X[0][b] = cadd(u, tb);
        X[1][b] = csub(u, tb);
        T = cmul(T, c4p);
    }
}

// stride-1 radix-2 via lane exchange (pair partner = lane^1), 8-element tile
__device__ inline void r2_shfl8(float2 X[2][4], bool ev) {
    #pragma unroll
    for (int c = 0; c < 2; c++)
        #pragma unroll
        for (int b = 0; b < 4; b++) {
            float2 o = f2(__shfl_xor(X[c][b].x, 1, 64), __shfl_xor(X[c][b].y, 1, 64));
            X[c][b] = ev ? cadd(X[c][b], o) : csub(o, X[c][b]);
        }
}

// ---------------------------- fused convert x->bf16 + xsum[b,d] = sum_n x (one pass)
__global__ void convert_reduce(const float* __restrict__ x, __bf16* __restrict__ xb,
                               float* __restrict__ xsum) {
    int b = blockIdx.z;
    int d = blockIdx.y * 256 + threadIdx.x;
    int n0 = blockIdx.x * 256;
    const float* p = x + ((size_t)b * PN + n0) * PD + d;
    __bf16* q = xb + ((size_t)b * PN + n0) * PD + d;
    float s = 0.0f;
    #pragma unroll 4
    for (int i = 0; i < 256; i++) {
        float v = p[(size_t)i * PD];
        s += v;
        q[(size_t)i * PD] = (__bf16)v;
    }
    atomicAdd(&xsum[b * PD + d], s);
}

// ------------------------- transpose+convert w_v, w_o -> bf16 N x K (LDS 64x64 tiles)
__global__ void transpose_w(const float* __restrict__ wv, const float* __restrict__ wo,
                            __bf16* __restrict__ wvt, __bf16* __restrict__ wot) {
    __shared__ float t[64][65];
    const float* src = blockIdx.z ? wo : wv;
    __bf16* dst = blockIdx.z ? wot : wvt;
    int r0 = blockIdx.y * 64, c0 = blockIdx.x * 64;
    int lr = threadIdx.x >> 6, lc = threadIdx.x & 63;
    #pragma unroll
    for (int i = 0; i < 16; i++)
        t[lr + 4 * i][lc] = src[(size_t)(r0 + lr + 4 * i) * PD + c0 + lc];
    __syncthreads();
    #pragma unroll
    for (int i = 0; i < 16; i++)
        dst[(size_t)(c0 + lr + 4 * i) * PD + r0 + lc] = (__bf16)t[lc][lr + 4 * i];
}

// --------------------------------- bar_q = (xsum/N) @ w_q, then LayerNorm over DH=64
// split-K: 4 waves each dot 256 k's for the same 64 cols; wave 0 combines + LN
__global__ void barq_ln(const float* __restrict__ xsum, const float* __restrict__ w_q,
                        const float* __restrict__ ln_g, const float* __restrict__ ln_b,
                        float* __restrict__ bar_ln) {
    int b = blockIdx.y;
    int lane = threadIdx.x & 63;
    int w = threadIdx.x >> 6;
    int c = blockIdx.x * 64 + lane;
    const float* xs = xsum + b * PD + w * 256;
    const float* wq = w_q + (size_t)(w * 256) * PD + c;
    float acc = 0.0f;
    for (int k = 0; k < 256; k++) acc += xs[k] * wq[(size_t)k * PD];
    __shared__ float part[4][64];
    part[w][lane] = acc;
    __syncthreads();
    if (w == 0) {
        float bar = (part[0][lane] + part[1][lane] + part[2][lane] + part[3][lane])
                    * (1.0f / (float)PN);
        float mu = bar;
        for (int o = 32; o > 0; o >>= 1) mu += __shfl_xor(mu, o, 64);
        mu *= (1.0f / 64.0f);
        float d0 = bar - mu;
        float vv = d0 * d0;
        for (int o = 32; o > 0; o >>= 1) vv += __shfl_xor(vv, o, 64);
        vv *= (1.0f / 64.0f);
        bar_ln[b * PD + c] = d0 * rsqrtf(vv + 1e-5f) * ln_g[lane] + ln_b[lane];
    }
}

// ---------------------------- t_gate = gelu(bar@gate_w1); t_wrm = gelu(bar@wrm_w1)
__global__ void small1(const float* __restrict__ bar_ln, const float* __restrict__ gw1,
                       const float* __restrict__ ww1, float* __restrict__ tg,
                       float* __restrict__ tw) {
    int bh = blockIdx.x;
    int j = threadIdx.x;
    __shared__ float bl[PDH];
    if (j < PDH) bl[j] = bar_ln[bh * PDH + j];
    __syncthreads();
    float a1 = 0.0f, a2 = 0.0f;
    for (int k = 0; k < PDH; k++) {
        float bv = bl[k];
        a1 += bv * gw1[k * PGH + j];
        a2 += bv * ww1[k * PGH + j];
    }
    tg[bh * PGH + j] = gelu_exact(a1);
    tw[bh * PGH + j] = gelu_exact(a2);
}

// ---------------------- g_raw = t_gate@gate_w2 (64x16384); s = t_wrm@wrm_w2 (64x8192)
__global__ void small2(const float* __restrict__ tg, const float* __restrict__ tw,
                       const float* __restrict__ gw2, const float* __restrict__ ww2,
                       float* __restrict__ g_raw, float* __restrict__ s_full) {
    int chunk = blockIdx.x;
    int bh0 = blockIdx.y * 8;
    bool isg = chunk < 64;
    const float* t = isg ? tg : tw;
    const float* w2 = isg ? gw2 : ww2;
    int stride = isg ? (2 * PN) : PN;
    int col = (isg ? chunk : chunk - 64) * 256 + threadIdx.x;
    __shared__ float tl[8][PGH];
    #pragma unroll
    for (int i = 0; i < 8; i++) tl[i][threadIdx.x] = t[(bh0 + i) * PGH + threadIdx.x];
    __syncthreads();
    float acc[8] = {0, 0, 0, 0, 0, 0, 0, 0};
    for (int k = 0; k < PGH; k++) {
        float w = w2[(size_t)k * stride + col];
        #pragma unroll
        for (int i = 0; i < 8; i++) acc[i] += tl[i][k] * w;
    }
    #pragma unroll
    for (int i = 0; i < 8; i++) {
        if (isg) g_raw[(size_t)(bh0 + i) * (2 * PN) + col] = acc[i];
        else     s_full[(size_t)(bh0 + i) * PN + col] = acc[i];
    }
}

// --------------------------------------------- GEMM1: C = A * Bt^T, pair-layout output
__global__ __launch_bounds__(256) void gemm_pair(const __bf16* __restrict__ A,
                                                 const __bf16* __restrict__ Bt,
                                                 u32* __restrict__ vt) {
    constexpr int K = PD, LDK = 32;
    __shared__ __attribute__((aligned(16))) __bf16 As[128 * LDK];
    __shared__ __attribute__((aligned(16))) __bf16 Bs[128 * LDK];
    const int tid = threadIdx.x;
    const int lane = tid & 63;
    const int wave = tid >> 6;
    const int wm = (wave >> 1) << 6;
    const int wn = (wave & 1) << 6;
    const int tileM = blockIdx.y << 7;
    const int tileN = blockIdx.x << 7;
    const int r = tid >> 2;
    const int cg = tid & 3;
    const int mrow = lane & 15;
    const int k0 = (lane >> 4) << 3;

    f32x4 acc[4][4] = {};
    const __bf16* Aptr = A + (size_t)(tileM + r) * K + cg * 8;
    const __bf16* Bptr = Bt + (size_t)(tileN + r) * K + cg * 8;

    for (int kt = 0; kt < K; kt += 32) {
        __syncthreads();
        ASYNC_COPY16(Aptr + kt,                  As + tid * 8);
        ASYNC_COPY16(Aptr + (size_t)64 * K + kt, As + 64 * LDK + tid * 8);
        ASYNC_COPY16(Bptr + kt,                  Bs + tid * 8);
        ASYNC_COPY16(Bptr + (size_t)64 * K + kt, Bs + 64 * LDK + tid * 8);
        __syncthreads();
        bf16x8 af[4], bfr[4];
        #pragma unroll
        for (int i = 0; i < 4; i++) af[i]  = *(const bf16x8*)&As[(wm + i * 16 + mrow) * LDK + k0];
        #pragma unroll
        for (int j = 0; j < 4; j++) bfr[j] = *(const bf16x8*)&Bs[(wn + j * 16 + mrow) * LDK + k0];
        #pragma unroll
        for (int i = 0; i < 4; i++)
            #pragma unroll
            for (int j = 0; j < 4; j++)
                acc[i][j] = __builtin_amdgcn_mfma_f32_16x16x32_bf16(af[i], bfr[j], acc[i][j], 0, 0, 0);
    }

    const int rq = (lane >> 4) << 2;
    const bool evl = (lane & 1) == 0;
    #pragma unroll
    for (int i = 0; i < 4; i++) {
        int grow = tileM + wm + i * 16 + rq;
        int b = grow >> 13;
        int nb = grow & 8191;
        #pragma unroll
        for (int j = 0; j < 4; j++) {
            u32 w[4];
            #pragma unroll
            for (int rr = 0; rr < 4; rr++) {
                float a = acc[i][j][rr];
                float o = __shfl_xor(a, 1, 64);
                w[rr] = packbf(a, o);
            }
            if (evl) {
                int col = tileN + wn + j * 16 + mrow;
                size_t idx = ((size_t)b * 512 + (col >> 1)) * PN + nb;
                *(uint4*)(vt + idx) = make_uint4(w[0], w[1], w[2], w[3]);
            }
        }
    }
}

// ----------------------------- GEMM2: C = Y * Bt^T with Y given in pair layout (=Y^T)
__global__ __launch_bounds__(256) void gemm_ta(const u32* __restrict__ yt,
                                               const __bf16* __restrict__ Bt,
                                               float* __restrict__ Cf) {
    constexpr int K = PD, Nc = PD, LDKA = 40, LDKB = 32;
    __shared__ __attribute__((aligned(16))) __bf16 As[128 * LDKA];
    __shared__ __attribute__((aligned(16))) __bf16 Bs[128 * LDKB];
    u32* As32 = (u32*)As;
    const int tid = threadIdx.x;
    const int lane = tid & 63;
    const int wave = tid >> 6;
    const int wm = (wave >> 1) << 6;
    const int wn = (wave & 1) << 6;
    const int tileM = blockIdx.y << 7;
    const int tileN = blockIdx.x << 7;
    const int r = tid >> 2;
    const int cg = tid & 3;
    const int mrow = lane & 15;
    const int k0 = (lane >> 4) << 3;
    const int prow = tid & 7;
    const int seg = tid >> 3;

    const int b = tileM >> 13;
    const int n0 = tileM & 8191;
    const u32* abase = yt + ((size_t)b * 512 + prow) * PN + n0 + seg * 4;
    const __bf16* Bptr = Bt + (size_t)(tileN + r) * K + cg * 8;

    f32x4 acc[4][4] = {};
    uint4 pa0 = *(const uint4*)(abase);
    uint4 pa1 = *(const uint4*)(abase + (size_t)8 * PN);

    for (int kt = 0; kt < K; kt += 32) {
        __syncthreads();
        {
            int m0 = seg * 4;
            As32[(m0 + 0) * 20 + prow] = pa0.x;
            As32[(m0 + 1) * 20 + prow] = pa0.y;
            As32[(m0 + 2) * 20 + prow] = pa0.z;
            As32[(m0 + 3) * 20 + prow] = pa0.w;
            As32[(m0 + 0) * 20 + prow + 8] = pa1.x;
            As32[(m0 + 1) * 20 + prow + 8] = pa1.y;
            As32[(m0 + 2) * 20 + prow + 8] = pa1.z;
            As32[(m0 + 3) * 20 + prow + 8] = pa1.w;
        }
        ASYNC_COPY16(Bptr + kt,                  Bs + tid * 8);
        ASYNC_COPY16(Bptr + (size_t)64 * K + kt, Bs + 64 * LDKB + tid * 8);
        if (kt + 32 < K) {
            const u32* nxt = abase + (size_t)((kt >> 1) + 16) * PN;
            pa0 = *(const uint4*)(nxt);
            pa1 = *(const uint4*)(nxt + (size_t)8 * PN);
        }
        __syncthreads();
        bf16x8 af[4], bfr[4];
        #pragma unroll
        for (int i = 0; i < 4; i++) af[i]  = *(const bf16x8*)&As[(wm + i * 16 + mrow) * LDKA + k0];
        #pragma unroll
        for (int j = 0; j < 4; j++) bfr[j] = *(const bf16x8*)&Bs[(wn + j * 16 + mrow) * LDKB + k0];
        #pragma unroll
        for (int i = 0; i < 4; i++)
            #pragma unroll
            for (int j = 0; j < 4; j++)
                acc[i][j] = __builtin_amdgcn_mfma_f32_16x16x32_bf16(af[i], bfr[j], acc[i][j], 0, 0, 0);
    }

    const int rq = (lane >> 4) << 2;
    #pragma unroll
    for (int i = 0; i < 4; i++) {
        #pragma unroll
        for (int rr = 0; rr < 4; rr++) {
            int row = tileM + wm + i * 16 + rq + rr;
            size_t base = (size_t)row * Nc + tileN + wn + mrow;
            #pragma unroll
            for (int j = 0; j < 4; j++) Cf[base + j * 16] = acc[i][j][rr];
        }
    }
}

// ------------------------------------------------- FFT conv + hadamard/scale epilogue
// 1024 threads, 8 elems/thread, radix-8 per LDS round trip. 9 barriers.
// No min-waves clause: round-4's __launch_bounds__(1024,8) forced VGPR<=~32 and
// spilled ~290MB/dispatch to scratch (WRITE_SIZE 352MB vs 66MB expected).
// Unconstrained, the live set (~16 data VGPRs + overhead) should land <=64
// -> 2 blocks/CU (LDS 2x64KB) without any scratch traffic.
__global__ __launch_bounds__(1024) void fftconv(const u32* __restrict__ vt,
                                                const float* __restrict__ g_raw,
                                                const float* __restrict__ s_full,
                                                u32* __restrict__ yt) {
    __shared__ float2 Z[PN];   // 64 KB
    const int tid = threadIdx.x;           // 0..1023
    const int row = blockIdx.x;            // b*512 + pair
    const int bh = row >> 5;
    const u32* vp = vt + (size_t)row * PN;
    const bool ev = (tid & 1) == 0;

    // ---- P1: global gather -> fwd layers 4096,2048,1024 -> LDS
    {
        float2 X[2][4];
        #pragma unroll
        for (int c = 0; c < 2; c++)
            #pragma unroll
            for (int b = 0; b < 4; b++) {
                u32 pw = vp[tid + c * 4096 + b * 1024];
                bf16x2 pp = *(bf16x2*)&pw;
                X[c][b] = f2((float)pp.x, (float)pp.y);
            }
        fwd8_layers<10>(X, tid);
        #pragma unroll
        for (int c = 0; c < 2; c++)
            #pragma unroll
            for (int b = 0; b < 4; b++)
                Z[PHYS(tid + c * 4096 + b * 1024)] = X[c][b];
    }
    __syncthreads();

    // ---- P2: fwd layers 512,256,128
    {
        const int base = ((tid >> 7) << 10) + (tid & 127);
        float2 X[2][4];
        #pragma unroll
        for (int c = 0; c < 2; c++)
            #pragma unroll
            for (int b = 0; b < 4; b++)
                X[c][b] = Z[PHYS(base + c * 512 + b * 128)];
        fwd8_layers<7>(X, tid & 127);
        #pragma unroll
        for (int c = 0; c < 2; c++)
            #pragma unroll
            for (int b = 0; b < 4; b++)
                Z[PHYS(base + c * 512 + b * 128)] = X[c][b];
    }
    __syncthreads();

    // ---- P3: fwd layers 64,32,16
    {
        const int base = ((tid >> 4) << 7) + (tid & 15);
        float2 X[2][4];
        #pragma unroll
        for (int c = 0; c < 2; c++)
            #pragma unroll
            for (int b = 0; b < 4; b++)
                X[c][b] = Z[PHYS(base + c * 64 + b * 16)];
        fwd8_layers<4>(X, tid & 15);
        #pragma unroll
        for (int c = 0; c < 2; c++)
            #pragma unroll
            for (int b = 0; b < 4; b++)
                Z[PHYS(base + c * 64 + b * 16)] = X[c][b];
    }
    __syncthreads();

    // ---- P4: fwd layers 8,4,2 + stride-1 radix-2 via shfl
    {
        const int base = ((tid >> 1) << 4) + (tid & 1);
        float2 X[2][4];
        #pragma unroll
        for (int c = 0; c < 2; c++)
            #pragma unroll
            for (int b = 0; b < 4; b++)
                X[c][b] = Z[PHYS(base + c * 8 + b * 2)];
        fwd8_layers<1>(X, tid & 1);
        r2_shfl8(X, ev);
        #pragma unroll
        for (int c = 0; c < 2; c++)
            #pragma unroll
            for (int b = 0; b < 4; b++)
                Z[PHYS(base + c * 8 + b * 2)] = X[c][b];
    }
    __syncthreads();

    // ---- spectral stage in bitrev addressing
    {
        const float* gr = g_raw + (size_t)bh * (2 * PN);
        const float* gi = gr + PN;
        for (int m = tid; m < PN / 2 + 1; m += 1024) {
            int p  = (m < PN / 2) ? 2 * m : 1;
            int k  = __brev((unsigned)p) >> 19;
            int Nk = (PN - k) & (PN - 1);
            int qd = __brev((unsigned)Nk) >> 19;
            float2 Za = Z[PHYS(p)], Zb = Z[PHYS(qd)];
            float v1r = 0.5f * (Za.x + Zb.x), v1i = 0.5f * (Za.y - Zb.y);
            float v2r = 0.5f * (Za.y + Zb.y), v2i = 0.5f * (Zb.x - Za.x);
            float grk = gr[k],  gik = gi[k];
            float grn = gr[Nk], gin = gi[Nk];
            float y1r  = v1r * grk - v1i * gik, y1i  = v1r * gik + v1i * grk;
            float y2r  = v2r * grk - v2i * gik, y2i  = v2r * gik + v2i * grk;
            float y1nr = v1r * grn + v1i * gin, y1ni = v1r * gin - v1i * grn;
            float y2nr = v2r * grn + v2i * gin, y2ni = v2r * gin - v2i * grn;
            float ys1r = 0.5f * (y1r + y1nr), ys1i = 0.5f * (y1i - y1ni);
            float ys2r = 0.5f * (y2r + y2nr), ys2i = 0.5f * (y2i - y2ni);
            Z[PHYS(p)] = f2(ys1r - ys2i, ys1i + ys2r);
            if (qd != p) Z[PHYS(qd)] = f2(ys1r + ys2i, ys2r - ys1i);
        }
    }
    __syncthreads();

    // ---- P5: stride-1 radix-2 via shfl + inv layers 2,4,8
    {
        const int base = ((tid >> 1) << 4) + (tid & 1);
        float2 X[2][4];
        #pragma unroll
        for (int c = 0; c < 2; c++)
            #pragma unroll
            for (int b = 0; b < 4; b++)
                X[c][b] = Z[PHYS(base + c * 8 + b * 2)];
        r2_shfl8(X, ev);
        inv8_layers<1>(X, tid & 1);
        #pragma unroll
        for (int c = 0; c < 2; c++)
            #pragma unroll
            for (int b = 0; b < 4; b++)
                Z[PHYS(base + c * 8 + b * 2)] = X[c][b];
    }
    __syncthreads();

    // ---- P6: inv layers 16,32,64
    {
        const int base = ((tid >> 4) << 7) + (tid & 15);
        float2 X[2][4];
        #pragma unroll
        for (int c = 0; c < 2; c++)
            #pragma unroll
            for (int b = 0; b < 4; b++)
                X[c][b] = Z[PHYS(base + c * 64 + b * 16)];
        inv8_layers<4>(X, tid & 15);
        #pragma unroll
        for (int c = 0; c < 2; c++)
            #pragma unroll
            for (int b = 0; b < 4; b++)
                Z[PHYS(base + c * 64 + b * 16)] = X[c][b];
    }
    __syncthreads();

    // ---- P7: inv layers 128,256,512
    {
        const int base = ((tid >> 7) << 10) + (tid & 127);
        float2 X[2][4];
        #pragma unroll
        for (int c = 0; c < 2; c++)
            #pragma unroll
            for (int b = 0; b < 4; b++)
                X[c][b] = Z[PHYS(base + c * 512 + b * 128)];
        inv8_layers<7>(X, tid & 127);
        #pragma unroll
        for (int c = 0; c < 2; c++)
            #pragma unroll
            for (int b = 0; b < 4; b++)
                Z[PHYS(base + c * 512 + b * 128)] = X[c][b];
    }
    __syncthreads();

    // ---- P8: inv layers 1024,2048,4096
    {
        float2 X[2][4];
        #pragma unroll
        for (int c = 0; c < 2; c++)
            #pragma unroll
            for (int b = 0; b < 4; b++)
                X[c][b] = Z[PHYS(tid + c * 4096 + b * 1024)];
        inv8_layers<10>(X, tid);
        #pragma unroll
        for (int c = 0; c < 2; c++)
            #pragma unroll
            for (int b = 0; b < 4; b++)
                Z[PHYS(tid + c * 4096 + b * 1024)] = X[c][b];
    }
    __syncthreads();

    // ---- epilogue: v_tilde + second-butterfly(s * first-butterfly(v_tilde))
    // Z fully inverse-transformed (natural order, unnormalized).
    {
        const float* sp = s_full + (size_t)bh * PN;
        u32* yp = yt + (size_t)row * PN;
        const float inv = 1.0f / (float)PN;
        const float I2 = 0.70710678118654752440f;
        const int nb = tid;            // 0..1023
        const int n0 = nb * 8;
        const int np0 = nb * 4;
        u32 ou[8];
        #pragma unroll
        for (int pp = 0; pp < 4; pp++) {
            float2 z0 = Z[PHYS(n0 + 2 * pp)];
            float2 z1 = Z[PHYS(n0 + 2 * pp + 1)];
            float s0  = sp[np0 + pp];
            float s1v = sp[np0 + pp + PN / 2];
            float ax = z0.x * inv, ay = z0.y * inv;
            float bx = z1.x * inv, by = z1.y * inv;
            float wlx = (ax + bx) * I2 * s0, whx = (ax - bx) * I2 * s1v;
            float evx = (wlx + whx) * I2,   odx = (wlx - whx) * I2;
            float wly = (ay + by) * I2 * s0, why = (ay - by) * I2 * s1v;
            float evy = (wly + why) * I2,   ody = (wly - why) * I2;
            ou[2 * pp]     = packbf(ax + evx, ay + evy);
            ou[2 * pp + 1] = packbf(bx + odx, by + ody);
        }
        *(uint4*)(yp + n0)     = make_uint4(ou[0], ou[1], ou[2], ou[3]);
        *(uint4*)(yp + n0 + 4) = make_uint4(ou[4], ou[5], ou[6], ou[7]);
    }
}

// ================================================================ launcher
extern "C" void kernel_launch(void* const* d_in, const int* in_sizes, int n_in,
                              void* d_out, int out_size, void* d_ws, size_t ws_size,
                              hipStream_t stream) {
    const float* x    = (const float*)d_in[0];
    const float* w_q  = (const float*)d_in[1];
    const float* w_v  = (const float*)d_in[2];
    const float* w_o  = (const float*)d_in[3];
    const float* ln_g = (const float*)d_in[4];
    const float* ln_b = (const float*)d_in[5];
    const float* gw1  = (const float*)d_in[6];
    const float* gw2  = (const float*)d_in[7];
    const float* ww1  = (const float*)d_in[8];
    const float* ww2  = (const float*)d_in[9];
    float* out = (float*)d_out;

    const size_t XE = (size_t)PB * PN * PD;        // 33554432
    __bf16* xb   = (__bf16*)d_ws;                  // x bf16; later reused: fft out (pair)
    __bf16* vb   = xb + XE;                        // gemm1 out (pair layout)
    __bf16* wvt  = vb + XE;
    __bf16* wot  = wvt + (size_t)PD * PD;
    float*  xsum = (float*)(wot + (size_t)PD * PD);
    float*  bar  = xsum + PB * PD;
    float*  tg   = bar + PB * PD;
    float*  tw   = tg + 64 * PGH;
    float*  graw = tw + 64 * PGH;
    float*  sful = graw + (size_t)64 * 2 * PN;

    hipMemsetAsync(xsum, 0, PB * PD * sizeof(float), stream);

    convert_reduce<<<dim3(PN / 256, PD / 256, PB), 256, 0, stream>>>(x, xb, xsum);
    transpose_w<<<dim3(16, 16, 2), 256, 0, stream>>>(w_v, w_o, wvt, wot);
    barq_ln<<<dim3(PD / 64, PB), 256, 0, stream>>>(xsum, w_q, ln_g, ln_b, bar);
    small1<<<PB * PH, 256, 0, stream>>>(bar, gw1, ww1, tg, tw);
    small2<<<dim3(96, 8), 256, 0, stream>>>(tg, tw, gw2, ww2, graw, sful);
    // v = x @ w_v, written directly in pair-transposed layout
    gemm_pair<<<dim3(PD / 128, PB * PN / 128), 256, 0, stream>>>(xb, wvt, (u32*)vb);
    // FFT conv: vb (pair) -> xb (pair)
    fftconv<<<PB * 512, 1024, 0, stream>>>((const u32*)vb, graw, sful, (u32*)xb);
    // out = y @ w_o, A staged from pair layout
    gemm_ta<<<dim3(PD / 128, PB * PN / 128), 256, 0, stream>>>((const u32*)xb, wot, out);
}

// Round 6
// 679.889 us; speedup vs baseline: 1.1201x; 1.0678x over previous
//
#include <hip/hip_runtime.h>
#include <hip/hip_bf16.h>
#include <math.h>

#define PB 4
#define PN 8192
#define PD 1024
#define PH 16
#define PDH 64
#define PGH 256

typedef __bf16 bf16x8 __attribute__((ext_vector_type(8)));
typedef __bf16 bf16x2 __attribute__((ext_vector_type(2)));
typedef float f32x4 __attribute__((ext_vector_type(4)));
typedef unsigned int u32;
typedef unsigned short u16;

typedef __attribute__((address_space(3))) void lds_void_t;
typedef const __attribute__((address_space(1))) void gbl_void_t;
#define ASYNC_COPY16(gp, lp) \
    __builtin_amdgcn_global_load_lds((gbl_void_t*)(gp), (lds_void_t*)(lp), 16, 0, 0)

__device__ inline float gelu_exact(float x) {
    return 0.5f * x * (1.0f + erff(x * 0.70710678118654752440f));
}

__device__ inline float2 f2(float x, float y) { return make_float2(x, y); }
__device__ inline float2 cadd(float2 a, float2 b) { return f2(a.x + b.x, a.y + b.y); }
__device__ inline float2 csub(float2 a, float2 b) { return f2(a.x - b.x, a.y - b.y); }
__device__ inline float2 cmul(float2 a, float2 b) {
    return f2(a.x * b.x - a.y * b.y, a.x * b.y + a.y * b.x);
}

// XOR swizzle: uniform ~4-way (b64 floor) for every access pattern in the FFT
#define PHYS(i) ((i) ^ (((i) >> 4) & 15))

// pack two floats to bf16x2-in-u32 (low = first)
__device__ inline u32 packbf(float a, float b) {
    __bf16 ba = (__bf16)a, bb = (__bf16)b;
    return (u32)(*(u16*)&ba) | ((u32)(*(u16*)&bb) << 16);
}

// ---------------------------- fused convert x->bf16 + xsum[b,d] = sum_n x (one pass)
__global__ void convert_reduce(const float* __restrict__ x, __bf16* __restrict__ xb,
                               float* __restrict__ xsum) {
    int b = blockIdx.z;
    int d = blockIdx.y * 256 + threadIdx.x;
    int n0 = blockIdx.x * 256;
    const float* p = x + ((size_t)b * PN + n0) * PD + d;
    __bf16* q = xb + ((size_t)b * PN + n0) * PD + d;
    float s = 0.0f;
    #pragma unroll 4
    for (int i = 0; i < 256; i++) {
        float v = p[(size_t)i * PD];
        s += v;
        q[(size_t)i * PD] = (__bf16)v;
    }
    atomicAdd(&xsum[b * PD + d], s);
}

// ------------------------- transpose+convert w_v, w_o -> bf16 N x K (LDS 64x64 tiles)
__global__ void transpose_w(const float* __restrict__ wv, const float* __restrict__ wo,
                            __bf16* __restrict__ wvt, __bf16* __restrict__ wot) {
    __shared__ float t[64][65];
    const float* src = blockIdx.z ? wo : wv;
    __bf16* dst = blockIdx.z ? wot : wvt;
    int r0 = blockIdx.y * 64, c0 = blockIdx.x * 64;
    int lr = threadIdx.x >> 6, lc = threadIdx.x & 63;
    #pragma unroll
    for (int i = 0; i < 16; i++)
        t[lr + 4 * i][lc] = src[(size_t)(r0 + lr + 4 * i) * PD + c0 + lc];
    __syncthreads();
    #pragma unroll
    for (int i = 0; i < 16; i++)
        dst[(size_t)(c0 + lr + 4 * i) * PD + r0 + lc] = (__bf16)t[lc][lr + 4 * i];
}

// --------------------------------- bar_q = (xsum/N) @ w_q, then LayerNorm over DH=64
__global__ void barq_ln(const float* __restrict__ xsum, const float* __restrict__ w_q,
                        const float* __restrict__ ln_g, const float* __restrict__ ln_b,
                        float* __restrict__ bar_ln) {
    int b = blockIdx.y;
    int lane = threadIdx.x & 63;
    int w = threadIdx.x >> 6;
    int c = blockIdx.x * 64 + lane;
    const float* xs = xsum + b * PD + w * 256;
    const float* wq = w_q + (size_t)(w * 256) * PD + c;
    float acc = 0.0f;
    for (int k = 0; k < 256; k++) acc += xs[k] * wq[(size_t)k * PD];
    __shared__ float part[4][64];
    part[w][lane] = acc;
    __syncthreads();
    if (w == 0) {
        float bar = (part[0][lane] + part[1][lane] + part[2][lane] + part[3][lane])
                    * (1.0f / (float)PN);
        float mu = bar;
        for (int o = 32; o > 0; o >>= 1) mu += __shfl_xor(mu, o, 64);
        mu *= (1.0f / 64.0f);
        float d0 = bar - mu;
        float vv = d0 * d0;
        for (int o = 32; o > 0; o >>= 1) vv += __shfl_xor(vv, o, 64);
        vv *= (1.0f / 64.0f);
        bar_ln[b * PD + c] = d0 * rsqrtf(vv + 1e-5f) * ln_g[lane] + ln_b[lane];
    }
}

// ---------------------------- t_gate = gelu(bar@gate_w1); t_wrm = gelu(bar@wrm_w1)
__global__ void small1(const float* __restrict__ bar_ln, const float* __restrict__ gw1,
                       const float* __restrict__ ww1, float* __restrict__ tg,
                       float* __restrict__ tw) {
    int bh = blockIdx.x;
    int j = threadIdx.x;
    __shared__ float bl[PDH];
    if (j < PDH) bl[j] = bar_ln[bh * PDH + j];
    __syncthreads();
    float a1 = 0.0f, a2 = 0.0f;
    for (int k = 0; k < PDH; k++) {
        float bv = bl[k];
        a1 += bv * gw1[k * PGH + j];
        a2 += bv * ww1[k * PGH + j];
    }
    tg[bh * PGH + j] = gelu_exact(a1);
    tw[bh * PGH + j] = gelu_exact(a2);
}

// ---------------------- g_raw = t_gate@gate_w2 (64x16384); s = t_wrm@wrm_w2 (64x8192)
__global__ void small2(const float* __restrict__ tg, const float* __restrict__ tw,
                       const float* __restrict__ gw2, const float* __restrict__ ww2,
                       float* __restrict__ g_raw, float* __restrict__ s_full) {
    int chunk = blockIdx.x;
    int bh0 = blockIdx.y * 8;
    bool isg = chunk < 64;
    const float* t = isg ? tg : tw;
    const float* w2 = isg ? gw2 : ww2;
    int stride = isg ? (2 * PN) : PN;
    int col = (isg ? chunk : chunk - 64) * 256 + threadIdx.x;
    __shared__ float tl[8][PGH];
    #pragma unroll
    for (int i = 0; i < 8; i++) tl[i][threadIdx.x] = t[(bh0 + i) * PGH + threadIdx.x];
    __syncthreads();
    float acc[8] = {0, 0, 0, 0, 0, 0, 0, 0};
    for (int k = 0; k < PGH; k++) {
        float w = w2[(size_t)k * stride + col];
        #pragma unroll
        for (int i = 0; i < 8; i++) acc[i] += tl[i][k] * w;
    }
    #pragma unroll
    for (int i = 0; i < 8; i++) {
        if (isg) g_raw[(size_t)(bh0 + i) * (2 * PN) + col] = acc[i];
        else     s_full[(size_t)(bh0 + i) * PN + col] = acc[i];
    }
}

// XCD-aware bijective remap of the 2048-block GEMM grid (grid = (8, 256)).
// Default round-robin puts the 8 N-tiles sharing one A-row-panel on 8 different
// XCD L2s. Remap: XCD k owns M-chunk [k*32,(k+1)*32) x all 8 N-tiles -> A panel
// fetched once per L2, B (2MB) L2-resident. 2048 % 8 == 0 -> bijective.
__device__ inline void xcd_swizzle(int& tileM, int& tileN) {
    int lin = blockIdx.x + (blockIdx.y << 3);   // gridDim.x == 8
    int xcd = lin & 7;
    int idx = lin >> 3;                          // [0, 256)
    int yy = (xcd << 5) + (idx >> 3);            // [0, 256)
    int xx = idx & 7;                            // [0, 8)
    tileM = yy << 7;
    tileN = xx << 7;
}

// --------------------------------------------- GEMM1: C = A * Bt^T, pair-layout output
__global__ __launch_bounds__(256) void gemm_pair(const __bf16* __restrict__ A,
                                                 const __bf16* __restrict__ Bt,
                                                 u32* __restrict__ vt) {
    constexpr int K = PD, LDK = 32;
    __shared__ __attribute__((aligned(16))) __bf16 As[128 * LDK];
    __shared__ __attribute__((aligned(16))) __bf16 Bs[128 * LDK];
    const int tid = threadIdx.x;
    const int lane = tid & 63;
    const int wave = tid >> 6;
    const int wm = (wave >> 1) << 6;
    const int wn = (wave & 1) << 6;
    int tileM, tileN;
    xcd_swizzle(tileM, tileN);
    const int r = tid >> 2;
    const int cg = tid & 3;
    const int mrow = lane & 15;
    const int k0 = (lane >> 4) << 3;

    f32x4 acc[4][4] = {};
    const __bf16* Aptr = A + (size_t)(tileM + r) * K + cg * 8;
    const __bf16* Bptr = Bt + (size_t)(tileN + r) * K + cg * 8;

    for (int kt = 0; kt < K; kt += 32) {
        __syncthreads();
        ASYNC_COPY16(Aptr + kt,                  As + tid * 8);
        ASYNC_COPY16(Aptr + (size_t)64 * K + kt, As + 64 * LDK + tid * 8);
        ASYNC_COPY16(Bptr + kt,                  Bs + tid * 8);
        ASYNC_COPY16(Bptr + (size_t)64 * K + kt, Bs + 64 * LDK + tid * 8);
        __syncthreads();
        bf16x8 af[4], bfr[4];
        #pragma unroll
        for (int i = 0; i < 4; i++) af[i]  = *(const bf16x8*)&As[(wm + i * 16 + mrow) * LDK + k0];
        #pragma unroll
        for (int j = 0; j < 4; j++) bfr[j] = *(const bf16x8*)&Bs[(wn + j * 16 + mrow) * LDK + k0];
        #pragma unroll
        for (int i = 0; i < 4; i++)
            #pragma unroll
            for (int j = 0; j < 4; j++)
                acc[i][j] = __builtin_amdgcn_mfma_f32_16x16x32_bf16(af[i], bfr[j], acc[i][j], 0, 0, 0);
    }

    const int rq = (lane >> 4) << 2;
    const bool evl = (lane & 1) == 0;
    #pragma unroll
    for (int i = 0; i < 4; i++) {
        int grow = tileM + wm + i * 16 + rq;
        int b = grow >> 13;
        int nb = grow & 8191;
        #pragma unroll
        for (int j = 0; j < 4; j++) {
            u32 w[4];
            #pragma unroll
            for (int rr = 0; rr < 4; rr++) {
                float a = acc[i][j][rr];
                float o = __shfl_xor(a, 1, 64);
                w[rr] = packbf(a, o);
            }
            if (evl) {
                int col = tileN + wn + j * 16 + mrow;
                size_t idx = ((size_t)b * 512 + (col >> 1)) * PN + nb;
                *(uint4*)(vt + idx) = make_uint4(w[0], w[1], w[2], w[3]);
            }
        }
    }
}

// ----------------------------- GEMM2: C = Y * Bt^T with Y given in pair layout (=Y^T)
__global__ __launch_bounds__(256) void gemm_ta(const u32* __restrict__ yt,
                                               const __bf16* __restrict__ Bt,
                                               float* __restrict__ Cf) {
    constexpr int K = PD, Nc = PD, LDKA = 40, LDKB = 32;
    __shared__ __attribute__((aligned(16))) __bf16 As[128 * LDKA];
    __shared__ __attribute__((aligned(16))) __bf16 Bs[128 * LDKB];
    u32* As32 = (u32*)As;
    const int tid = threadIdx.x;
    const int lane = tid & 63;
    const int wave = tid >> 6;
    const int wm = (wave >> 1) << 6;
    const int wn = (wave & 1) << 6;
    int tileM, tileN;
    xcd_swizzle(tileM, tileN);
    const int r = tid >> 2;
    const int cg = tid & 3;
    const int mrow = lane & 15;
    const int k0 = (lane >> 4) << 3;
    const int prow = tid & 7;
    const int seg = tid >> 3;

    const int b = tileM >> 13;
    const int n0 = tileM & 8191;
    const u32* abase = yt + ((size_t)b * 512 + prow) * PN + n0 + seg * 4;
    const __bf16* Bptr = Bt + (size_t)(tileN + r) * K + cg * 8;

    f32x4 acc[4][4] = {};
    uint4 pa0 = *(const uint4*)(abase);
    uint4 pa1 = *(const uint4*)(abase + (size_t)8 * PN);

    for (int kt = 0; kt < K; kt += 32) {
        __syncthreads();
        {
            int m0 = seg * 4;
            As32[(m0 + 0) * 20 + prow] = pa0.x;
            As32[(m0 + 1) * 20 + prow] = pa0.y;
            As32[(m0 + 2) * 20 + prow] = pa0.z;
            As32[(m0 + 3) * 20 + prow] = pa0.w;
            As32[(m0 + 0) * 20 + prow + 8] = pa1.x;
            As32[(m0 + 1) * 20 + prow + 8] = pa1.y;
            As32[(m0 + 2) * 20 + prow + 8] = pa1.z;
            As32[(m0 + 3) * 20 + prow + 8] = pa1.w;
        }
        ASYNC_COPY16(Bptr + kt,                  Bs + tid * 8);
        ASYNC_COPY16(Bptr + (size_t)64 * K + kt, Bs + 64 * LDKB + tid * 8);
        if (kt + 32 < K) {
            const u32* nxt = abase + (size_t)((kt >> 1) + 16) * PN;
            pa0 = *(const uint4*)(nxt);
            pa1 = *(const uint4*)(nxt + (size_t)8 * PN);
        }
        __syncthreads();
        bf16x8 af[4], bfr[4];
        #pragma unroll
        for (int i = 0; i < 4; i++) af[i]  = *(const bf16x8*)&As[(wm + i * 16 + mrow) * LDKA + k0];
        #pragma unroll
        for (int j = 0; j < 4; j++) bfr[j] = *(const bf16x8*)&Bs[(wn + j * 16 + mrow) * LDKB + k0];
        #pragma unroll
        for (int i = 0; i < 4; i++)
            #pragma unroll
            for (int j = 0; j < 4; j++)
                acc[i][j] = __builtin_amdgcn_mfma_f32_16x16x32_bf16(af[i], bfr[j], acc[i][j], 0, 0, 0);
    }

    const int rq = (lane >> 4) << 2;
    #pragma unroll
    for (int i = 0; i < 4; i++) {
        #pragma unroll
        for (int rr = 0; rr < 4; rr++) {
            int row = tileM + wm + i * 16 + rq + rr;
            size_t base = (size_t)row * Nc + tileN + wn + mrow;
            #pragma unroll
            for (int j = 0; j < 4; j++) Cf[base + j * 16] = acc[i][j][rr];
        }
    }
}

// ------------------------------------------------- FFT conv + hadamard/scale epilogue
// Round-1 proven structure (180us): 512 threads, radix-2^2 per stage, 4 independent
// butterflies/thread/stage (ILP), XOR-swizzled LDS, hoisted/incremental twiddles.
// Restructure attempts (radix-16 r3, radix-8 r5) both regressed to ~203us: same VALU
// work but long dependent chains killed ILP; occupancy was not the limiter (r3/r5 A/B).
__global__ __launch_bounds__(512) void fftconv(const u32* __restrict__ vt,
                                               const float* __restrict__ g_raw,
                                               const float* __restrict__ s_full,
                                               u32* __restrict__ yt) {
    __shared__ float2 Z[PN];   // 64 KB
    const int tid = threadIdx.x;           // 0..511
    const int row = blockIdx.x;            // b*512 + pair
    const int bh = row >> 5;
    const u32* vp = vt + (size_t)row * PN;

    #pragma unroll
    for (int it = 0; it < 2; it++) {
        int n0 = (tid + it * 512) * 8;
        uint4 u0 = *(const uint4*)(vp + n0);
        uint4 u1 = *(const uint4*)(vp + n0 + 4);
        u32 uu[8] = {u0.x, u0.y, u0.z, u0.w, u1.x, u1.y, u1.z, u1.w};
        #pragma unroll
        for (int m = 0; m < 8; m++) {
            bf16x2 p = *(bf16x2*)&uu[m];
            Z[PHYS(n0 + m)] = f2((float)p.x, (float)p.y);
        }
    }
    __syncthreads();

    // forward DIF: radix-4 stages s=11,9,7,5,3,1 then radix-2 s=0
    #pragma unroll
    for (int si = 0; si < 6; si++) {
        const int s = 11 - 2 * si;
        const int h = 1 << s;
        const float ang = -6.283185307179586f / (float)(4 * h);
        float sn, cs;
        __sincosf(ang * (float)(tid & (h - 1)), &sn, &cs);
        float2 w2 = f2(cs, sn);
        #pragma unroll
        for (int it = 0; it < 4; it++) {
            int q = tid + it * 512;
            int i = ((q >> s) << (s + 2)) + (q & (h - 1));
            float2 w1 = cmul(w2, w2);
            float2 a = Z[PHYS(i)],         bb = Z[PHYS(i + h)];
            float2 c = Z[PHYS(i + 2 * h)], d  = Z[PHYS(i + 3 * h)];
            float2 A0 = cadd(a, c);
            float2 C0 = cmul(csub(a, c), w2);
            float2 B0 = cadd(bb, d);
            float2 t  = cmul(csub(bb, d), w2);
            float2 D0 = f2(t.y, -t.x);               // * (-i)
            Z[PHYS(i)]         = cadd(A0, B0);
            Z[PHYS(i + h)]     = cmul(csub(A0, B0), w1);
            Z[PHYS(i + 2 * h)] = cadd(C0, D0);
            Z[PHYS(i + 3 * h)] = cmul(csub(C0, D0), w1);
            if (h == 2048) w2 = cmul(w2, f2(0.92387953251f, -0.38268343236f)); // cis(-pi/8)
        }
        __syncthreads();
    }
    #pragma unroll
    for (int it = 0; it < 8; it++) {               // radix-2 s=0, twiddle-free
        int i = 2 * (tid + it * 512);
        float2 u = Z[PHYS(i)], t = Z[PHYS(i + 1)];
        Z[PHYS(i)]     = cadd(u, t);
        Z[PHYS(i + 1)] = csub(u, t);
    }
    __syncthreads();

    // spectral stage in bitrev addressing
    const float* gr = g_raw + (size_t)bh * (2 * PN);
    const float* gi = gr + PN;
    for (int m = tid; m < PN / 2 + 1; m += 512) {
        int p  = (m < PN / 2) ? 2 * m : 1;
        int k  = __brev((unsigned)p) >> 19;
        int Nk = (PN - k) & (PN - 1);
        int qd = __brev((unsigned)Nk) >> 19;
        float2 Za = Z[PHYS(p)], Zb = Z[PHYS(qd)];
        float v1r = 0.5f * (Za.x + Zb.x), v1i = 0.5f * (Za.y - Zb.y);
        float v2r = 0.5f * (Za.y + Zb.y), v2i = 0.5f * (Zb.x - Za.x);
        float grk = gr[k],  gik = gi[k];
        float grn = gr[Nk], gin = gi[Nk];
        float y1r  = v1r * grk - v1i * gik, y1i  = v1r * gik + v1i * grk;
        float y2r  = v2r * grk - v2i * gik, y2i  = v2r * gik + v2i * grk;
        float y1nr = v1r * grn + v1i * gin, y1ni = v1r * gin - v1i * grn;
        float y2nr = v2r * grn + v2i * gin, y2ni = v2r * gin - v2i * grn;
        float ys1r = 0.5f * (y1r + y1nr), ys1i = 0.5f * (y1i - y1ni);
        float ys2r = 0.5f * (y2r + y2nr), ys2i = 0.5f * (y2i - y2ni);
        Z[PHYS(p)] = f2(ys1r - ys2i, ys1i + ys2r);
        if (qd != p) Z[PHYS(qd)] = f2(ys1r + ys2i, ys2r - ys1i);
    }
    __syncthreads();

    // inverse DIT: radix-4 stages s=0,2,4,6,8,10 then radix-2 s=12
    #pragma unroll
    for (int si = 0; si < 6; si++) {
        const int s = 2 * si;
        const int h = 1 << s;
        const float ang = 6.283185307179586f / (float)(4 * h);
        float sn, cs;
        __sincosf(ang * (float)(tid & (h - 1)), &sn, &cs);
        float2 w2a = f2(cs, sn);
        float2 w2b = (h == 1024) ? cmul(w2a, f2(0.70710678119f, 0.70710678119f)) : w2a;
        #pragma unroll
        for (int it = 0; it < 4; it++) {
            int q = tid + it * 512;
            int i = ((q >> s) << (s + 2)) + (q & (h - 1));
            float2 w2 = (it & 1) ? w2b : w2a;
            float2 w1 = cmul(w2, w2);
            float2 a = Z[PHYS(i)],         bb = Z[PHYS(i + h)];
            float2 c = Z[PHYS(i + 2 * h)], d  = Z[PHYS(i + 3 * h)];
            float2 tb = cmul(bb, w1);
            float2 p0 = cadd(a, tb), p1 = csub(a, tb);
            float2 td = cmul(d, w1);
            float2 q0 = cadd(c, td), q1 = csub(c, td);
            float2 wq0 = cmul(q0, w2);
            float2 e   = cmul(q1, w2);
            float2 ei  = f2(-e.y, e.x);              // * (+i)
            Z[PHYS(i)]         = cadd(p0, wq0);
            Z[PHYS(i + 2 * h)] = csub(p0, wq0);
            Z[PHYS(i + h)]     = cadd(p1, ei);
            Z[PHYS(i + 3 * h)] = csub(p1, ei);
        }
        __syncthreads();
    }
    {
        const float ang = 6.283185307179586f / (float)PN;
        float sn, cs;
        __sincosf(ang * (float)tid, &sn, &cs);
        float2 w = f2(cs, sn);
        #pragma unroll
        for (int it = 0; it < 8; it++) {           // radix-2 s=12, chained twiddle
            int q = tid + it * 512;
            float2 u = Z[PHYS(q)];
            float2 t = cmul(Z[PHYS(q + PN / 2)], w);
            Z[PHYS(q)]          = cadd(u, t);
            Z[PHYS(q + PN / 2)] = csub(u, t);
            w = cmul(w, f2(0.92387953251f, 0.38268343236f)); // cis(+pi/8)
        }
    }
    __syncthreads();

    // epilogue: v_tilde + second-butterfly(s * first-butterfly(v_tilde))
    const float* sp = s_full + (size_t)bh * PN;
    u32* yp = yt + (size_t)row * PN;
    const float inv = 1.0f / (float)PN;
    const float I2 = 0.70710678118654752440f;
    #pragma unroll
    for (int it = 0; it < 2; it++) {
        int nb = tid + it * 512;       // 0..1023
        int n0 = nb * 8;
        int np0 = nb * 4;
        u32 ou[8];
        #pragma unroll
        for (int pp = 0; pp < 4; pp++) {
            float2 z0 = Z[PHYS(n0 + 2 * pp)];
            float2 z1 = Z[PHYS(n0 + 2 * pp + 1)];
            float s0  = sp[np0 + pp];
            float s1v = sp[np0 + pp + PN / 2];
            float ax = z0.x * inv, ay = z0.y * inv;
            float bx = z1.x * inv, by = z1.y * inv;
            float wlx = (ax + bx) * I2 * s0, whx = (ax - bx) * I2 * s1v;
            float evx = (wlx + whx) * I2,   odx = (wlx - whx) * I2;
            float wly = (ay + by) * I2 * s0, why = (ay - by) * I2 * s1v;
            float evy = (wly + why) * I2,   ody = (wly - why) * I2;
            ou[2 * pp]     = packbf(ax + evx, ay + evy);
            ou[2 * pp + 1] = packbf(bx + odx, by + ody);
        }
        *(uint4*)(yp + n0)     = make_uint4(ou[0], ou[1], ou[2], ou[3]);
        *(uint4*)(yp + n0 + 4) = make_uint4(ou[4], ou[5], ou[6], ou[7]);
    }
}

// ================================================================ launcher
extern "C" void kernel_launch(void* const* d_in, const int* in_sizes, int n_in,
                              void* d_out, int out_size, void* d_ws, size_t ws_size,
                              hipStream_t stream) {
    const float* x    = (const float*)d_in[0];
    const float* w_q  = (const float*)d_in[1];
    const float* w_v  = (const float*)d_in[2];
    const float* w_o  = (const float*)d_in[3];
    const float* ln_g = (const float*)d_in[4];
    const float* ln_b = (const float*)d_in[5];
    const float* gw1  = (const float*)d_in[6];
    const float* gw2  = (const float*)d_in[7];
    const float* ww1  = (const float*)d_in[8];
    const float* ww2  = (const float*)d_in[9];
    float* out = (float*)d_out;

    const size_t XE = (size_t)PB * PN * PD;        // 33554432
    __bf16* xb   = (__bf16*)d_ws;                  // x bf16; later reused: fft out (pair)
    __bf16* vb   = xb + XE;                        // gemm1 out (pair layout)
    __bf16* wvt  = vb + XE;
    __bf16* wot  = wvt + (size_t)PD * PD;
    float*  xsum = (float*)(wot + (size_t)PD * PD);
    float*  bar  = xsum + PB * PD;
    float*  tg   = bar + PB * PD;
    float*  tw   = tg + 64 * PGH;
    float*  graw = tw + 64 * PGH;
    float*  sful = graw + (size_t)64 * 2 * PN;

    hipMemsetAsync(xsum, 0, PB * PD * sizeof(float), stream);

    convert_reduce<<<dim3(PN / 256, PD / 256, PB), 256, 0, stream>>>(x, xb, xsum);
    transpose_w<<<dim3(16, 16, 2), 256, 0, stream>>>(w_v, w_o, wvt, wot);
    barq_ln<<<dim3(PD / 64, PB), 256, 0, stream>>>(xsum, w_q, ln_g, ln_b, bar);
    small1<<<PB * PH, 256, 0, stream>>>(bar, gw1, ww1, tg, tw);
    small2<<<dim3(96, 8), 256, 0, stream>>>(tg, tw, gw2, ww2, graw, sful);
    // v = x @ w_v, written directly in pair-transposed layout
    gemm_pair<<<dim3(PD / 128, PB * PN / 128), 256, 0, stream>>>(xb, wvt, (u32*)vb);
    // FFT conv: vb (pair) -> xb (pair)
    fftconv<<<PB * 512, 512, 0, stream>>>((const u32*)vb, graw, sful, (u32*)xb);
    // out = y @ w_o, A staged from pair layout
    gemm_ta<<<dim3(PD / 128, PB * PN / 128), 256, 0, stream>>>((const u32*)xb, wot, out);
}

// Round 7
// 664.772 us; speedup vs baseline: 1.1455x; 1.0227x over previous
//
#include <hip/hip_runtime.h>
#include <hip/hip_bf16.h>
#include <math.h>

#define PB 4
#define PN 8192
#define PD 1024
#define PH 16
#define PDH 64
#define PGH 256

typedef __bf16 bf16x8 __attribute__((ext_vector_type(8)));
typedef __bf16 bf16x2 __attribute__((ext_vector_type(2)));
typedef float f32x4 __attribute__((ext_vector_type(4)));
typedef unsigned int u32;
typedef unsigned short u16;

typedef __attribute__((address_space(3))) void lds_void_t;
typedef const __attribute__((address_space(1))) void gbl_void_t;
#define ASYNC_COPY16(gp, lp) \
    __builtin_amdgcn_global_load_lds((gbl_void_t*)(gp), (lds_void_t*)(lp), 16, 0, 0)

__device__ inline float gelu_exact(float x) {
    return 0.5f * x * (1.0f + erff(x * 0.70710678118654752440f));
}

__device__ inline float2 f2(float x, float y) { return make_float2(x, y); }
__device__ inline float2 cadd(float2 a, float2 b) { return f2(a.x + b.x, a.y + b.y); }
__device__ inline float2 csub(float2 a, float2 b) { return f2(a.x - b.x, a.y - b.y); }
__device__ inline float2 cmul(float2 a, float2 b) {
    return f2(a.x * b.x - a.y * b.y, a.x * b.y + a.y * b.x);
}

// XOR swizzle: uniform ~4-way (b64 floor) for every access pattern in the FFT
#define PHYS(i) ((i) ^ (((i) >> 4) & 15))

// pack two floats to bf16x2-in-u32 (low = first)
__device__ inline u32 packbf(float a, float b) {
    __bf16 ba = (__bf16)a, bb = (__bf16)b;
    return (u32)(*(u16*)&ba) | ((u32)(*(u16*)&bb) << 16);
}

// ------------- fused convert x->bf16 + xsum (vectorized: 32B loads, 16B stores/lane)
__global__ void convert_reduce(const float* __restrict__ x, __bf16* __restrict__ xb,
                               float* __restrict__ xsum) {
    int b = blockIdx.z;
    int r = threadIdx.x >> 7;               // 0..1 (row parity)
    int dt = threadIdx.x & 127;
    int dq = dt * 8;                         // 8 consecutive d per thread
    int nbase = blockIdx.x * 128;
    float s[8] = {0, 0, 0, 0, 0, 0, 0, 0};
    for (int i = 0; i < 64; i++) {
        size_t row = (size_t)b * PN + nbase + i * 2 + r;
        const float* p = x + row * PD + dq;
        float4 f0 = *(const float4*)p;
        float4 f1 = *(const float4*)(p + 4);
        bf16x8 o;
        o[0] = (__bf16)f0.x; o[1] = (__bf16)f0.y; o[2] = (__bf16)f0.z; o[3] = (__bf16)f0.w;
        o[4] = (__bf16)f1.x; o[5] = (__bf16)f1.y; o[6] = (__bf16)f1.z; o[7] = (__bf16)f1.w;
        s[0] += f0.x; s[1] += f0.y; s[2] += f0.z; s[3] += f0.w;
        s[4] += f1.x; s[5] += f1.y; s[6] += f1.z; s[7] += f1.w;
        *(bf16x8*)(xb + row * PD + dq) = o;
    }
    __shared__ float red[128][9];            // +1 pad: avoid 16-way bank alias
    if (r == 1) {
        #pragma unroll
        for (int j = 0; j < 8; j++) red[dt][j] = s[j];
    }
    __syncthreads();
    if (r == 0) {
        #pragma unroll
        for (int j = 0; j < 8; j++)
            atomicAdd(&xsum[b * PD + dq + j], s[j] + red[dt][j]);
    }
}

// ------------------------- transpose+convert w_v, w_o -> bf16 N x K (LDS 64x64 tiles)
__global__ void transpose_w(const float* __restrict__ wv, const float* __restrict__ wo,
                            __bf16* __restrict__ wvt, __bf16* __restrict__ wot) {
    __shared__ float t[64][65];
    const float* src = blockIdx.z ? wo : wv;
    __bf16* dst = blockIdx.z ? wot : wvt;
    int r0 = blockIdx.y * 64, c0 = blockIdx.x * 64;
    int lr = threadIdx.x >> 6, lc = threadIdx.x & 63;
    #pragma unroll
    for (int i = 0; i < 16; i++)
        t[lr + 4 * i][lc] = src[(size_t)(r0 + lr + 4 * i) * PD + c0 + lc];
    __syncthreads();
    #pragma unroll
    for (int i = 0; i < 16; i++)
        dst[(size_t)(c0 + lr + 4 * i) * PD + r0 + lc] = (__bf16)t[lc][lr + 4 * i];
}

// --------------------------------- bar_q = (xsum/N) @ w_q, then LayerNorm over DH=64
__global__ void barq_ln(const float* __restrict__ xsum, const float* __restrict__ w_q,
                        const float* __restrict__ ln_g, const float* __restrict__ ln_b,
                        float* __restrict__ bar_ln) {
    int b = blockIdx.y;
    int lane = threadIdx.x & 63;
    int w = threadIdx.x >> 6;
    int c = blockIdx.x * 64 + lane;
    const float* xs = xsum + b * PD + w * 256;
    const float* wq = w_q + (size_t)(w * 256) * PD + c;
    float acc = 0.0f;
    for (int k = 0; k < 256; k++) acc += xs[k] * wq[(size_t)k * PD];
    __shared__ float part[4][64];
    part[w][lane] = acc;
    __syncthreads();
    if (w == 0) {
        float bar = (part[0][lane] + part[1][lane] + part[2][lane] + part[3][lane])
                    * (1.0f / (float)PN);
        float mu = bar;
        for (int o = 32; o > 0; o >>= 1) mu += __shfl_xor(mu, o, 64);
        mu *= (1.0f / 64.0f);
        float d0 = bar - mu;
        float vv = d0 * d0;
        for (int o = 32; o > 0; o >>= 1) vv += __shfl_xor(vv, o, 64);
        vv *= (1.0f / 64.0f);
        bar_ln[b * PD + c] = d0 * rsqrtf(vv + 1e-5f) * ln_g[lane] + ln_b[lane];
    }
}

// ---------------------------- t_gate = gelu(bar@gate_w1); t_wrm = gelu(bar@wrm_w1)
__global__ void small1(const float* __restrict__ bar_ln, const float* __restrict__ gw1,
                       const float* __restrict__ ww1, float* __restrict__ tg,
                       float* __restrict__ tw) {
    int bh = blockIdx.x;
    int j = threadIdx.x;
    __shared__ float bl[PDH];
    if (j < PDH) bl[j] = bar_ln[bh * PDH + j];
    __syncthreads();
    float a1 = 0.0f, a2 = 0.0f;
    for (int k = 0; k < PDH; k++) {
        float bv = bl[k];
        a1 += bv * gw1[k * PGH + j];
        a2 += bv * ww1[k * PGH + j];
    }
    tg[bh * PGH + j] = gelu_exact(a1);
    tw[bh * PGH + j] = gelu_exact(a2);
}

// ---------------------- g_raw = t_gate@gate_w2 (64x16384); s = t_wrm@wrm_w2 (64x8192)
__global__ void small2(const float* __restrict__ tg, const float* __restrict__ tw,
                       const float* __restrict__ gw2, const float* __restrict__ ww2,
                       float* __restrict__ g_raw, float* __restrict__ s_full) {
    int chunk = blockIdx.x;
    int bh0 = blockIdx.y * 8;
    bool isg = chunk < 64;
    const float* t = isg ? tg : tw;
    const float* w2 = isg ? gw2 : ww2;
    int stride = isg ? (2 * PN) : PN;
    int col = (isg ? chunk : chunk - 64) * 256 + threadIdx.x;
    __shared__ float tl[8][PGH];
    #pragma unroll
    for (int i = 0; i < 8; i++) tl[i][threadIdx.x] = t[(bh0 + i) * PGH + threadIdx.x];
    __syncthreads();
    float acc[8] = {0, 0, 0, 0, 0, 0, 0, 0};
    for (int k = 0; k < PGH; k++) {
        float w = w2[(size_t)k * stride + col];
        #pragma unroll
        for (int i = 0; i < 8; i++) acc[i] += tl[i][k] * w;
    }
    #pragma unroll
    for (int i = 0; i < 8; i++) {
        if (isg) g_raw[(size_t)(bh0 + i) * (2 * PN) + col] = acc[i];
        else     s_full[(size_t)(bh0 + i) * PN + col] = acc[i];
    }
}

// XCD-aware bijective remap of the 2048-block GEMM grid (grid = (8, 256)).
__device__ inline void xcd_swizzle(int& tileM, int& tileN) {
    int lin = blockIdx.x + (blockIdx.y << 3);   // gridDim.x == 8
    int xcd = lin & 7;
    int idx = lin >> 3;                          // [0, 256)
    int yy = (xcd << 5) + (idx >> 3);            // [0, 256)
    int xx = idx & 7;                            // [0, 8)
    tileM = yy << 7;
    tileN = xx << 7;
}

// --------------------------------------------- GEMM1: C = A * Bt^T, pair-layout output
// Min-2-phase double-buffer: stage tile k+1 into buf^1 BEFORE computing buf; one
// barrier/iter (was 2, with staging serialized). vmcnt(0) drain at the barrier now
// lands after a full MFMA phase of load flight.
__global__ __launch_bounds__(256) void gemm_pair(const __bf16* __restrict__ A,
                                                 const __bf16* __restrict__ Bt,
                                                 u32* __restrict__ vt) {
    constexpr int K = PD, LDK = 32;
    __shared__ __attribute__((aligned(16))) __bf16 As[2][128 * LDK];
    __shared__ __attribute__((aligned(16))) __bf16 Bs[2][128 * LDK];
    const int tid = threadIdx.x;
    const int lane = tid & 63;
    const int wave = tid >> 6;
    const int wm = (wave >> 1) << 6;
    const int wn = (wave & 1) << 6;
    int tileM, tileN;
    xcd_swizzle(tileM, tileN);
    const int r = tid >> 2;
    const int cg = tid & 3;
    const int mrow = lane & 15;
    const int k0 = (lane >> 4) << 3;

    f32x4 acc[4][4] = {};
    const __bf16* Aptr = A + (size_t)(tileM + r) * K + cg * 8;
    const __bf16* Bptr = Bt + (size_t)(tileN + r) * K + cg * 8;

    // prologue: stage tile 0 into buf 0
    ASYNC_COPY16(Aptr,                  &As[0][tid * 8]);
    ASYNC_COPY16(Aptr + (size_t)64 * K, &As[0][64 * LDK + tid * 8]);
    ASYNC_COPY16(Bptr,                  &Bs[0][tid * 8]);
    ASYNC_COPY16(Bptr + (size_t)64 * K, &Bs[0][64 * LDK + tid * 8]);
    __syncthreads();

    int cur = 0;
    for (int kt = 0; kt < K; kt += 32) {
        if (kt + 32 < K) {
            ASYNC_COPY16(Aptr + kt + 32,                  &As[cur ^ 1][tid * 8]);
            ASYNC_COPY16(Aptr + (size_t)64 * K + kt + 32, &As[cur ^ 1][64 * LDK + tid * 8]);
            ASYNC_COPY16(Bptr + kt + 32,                  &Bs[cur ^ 1][tid * 8]);
            ASYNC_COPY16(Bptr + (size_t)64 * K + kt + 32, &Bs[cur ^ 1][64 * LDK + tid * 8]);
        }
        bf16x8 af[4], bfr[4];
        #pragma unroll
        for (int i = 0; i < 4; i++) af[i]  = *(const bf16x8*)&As[cur][(wm + i * 16 + mrow) * LDK + k0];
        #pragma unroll
        for (int j = 0; j < 4; j++) bfr[j] = *(const bf16x8*)&Bs[cur][(wn + j * 16 + mrow) * LDK + k0];
        #pragma unroll
        for (int i = 0; i < 4; i++)
            #pragma unroll
            for (int j = 0; j < 4; j++)
                acc[i][j] = __builtin_amdgcn_mfma_f32_16x16x32_bf16(af[i], bfr[j], acc[i][j], 0, 0, 0);
        __syncthreads();
        cur ^= 1;
    }

    const int rq = (lane >> 4) << 2;
    const bool evl = (lane & 1) == 0;
    #pragma unroll
    for (int i = 0; i < 4; i++) {
        int grow = tileM + wm + i * 16 + rq;
        int b = grow >> 13;
        int nb = grow & 8191;
        #pragma unroll
        for (int j = 0; j < 4; j++) {
            u32 w[4];
            #pragma unroll
            for (int rr = 0; rr < 4; rr++) {
                float a = acc[i][j][rr];
                float o = __shfl_xor(a, 1, 64);
                w[rr] = packbf(a, o);
            }
            if (evl) {
                int col = tileN + wn + j * 16 + mrow;
                size_t idx = ((size_t)b * 512 + (col >> 1)) * PN + nb;
                *(uint4*)(vt + idx) = make_uint4(w[0], w[1], w[2], w[3]);
            }
        }
    }
}

// ----------------------------- GEMM2: C = Y * Bt^T with Y given in pair layout (=Y^T)
// Same min-2-phase: scatter/stage tile k+1 into buf^1 before computing buf.
__global__ __launch_bounds__(256) void gemm_ta(const u32* __restrict__ yt,
                                               const __bf16* __restrict__ Bt,
                                               float* __restrict__ Cf) {
    constexpr int K = PD, Nc = PD, LDKA = 40, LDKB = 32;
    __shared__ __attribute__((aligned(16))) __bf16 As[2][128 * LDKA];
    __shared__ __attribute__((aligned(16))) __bf16 Bs[2][128 * LDKB];
    const int tid = threadIdx.x;
    const int lane = tid & 63;
    const int wave = tid >> 6;
    const int wm = (wave >> 1) << 6;
    const int wn = (wave & 1) << 6;
    int tileM, tileN;
    xcd_swizzle(tileM, tileN);
    const int r = tid >> 2;
    const int cg = tid & 3;
    const int mrow = lane & 15;
    const int k0 = (lane >> 4) << 3;
    const int prow = tid & 7;
    const int seg = tid >> 3;
    const int m0 = seg * 4;

    const int b = tileM >> 13;
    const int n0 = tileM & 8191;
    const u32* abase = yt + ((size_t)b * 512 + prow) * PN + n0 + seg * 4;
    const __bf16* Bptr = Bt + (size_t)(tileN + r) * K + cg * 8;

    f32x4 acc[4][4] = {};

    // prologue: tile 0 scatter + B stage; prefetch tile 1 regs
    uint4 pa0 = *(const uint4*)(abase);
    uint4 pa1 = *(const uint4*)(abase + (size_t)8 * PN);
    {
        u32* a32 = (u32*)&As[0][0];
        a32[(m0 + 0) * 20 + prow] = pa0.x;
        a32[(m0 + 1) * 20 + prow] = pa0.y;
        a32[(m0 + 2) * 20 + prow] = pa0.z;
        a32[(m0 + 3) * 20 + prow] = pa0.w;
        a32[(m0 + 0) * 20 + prow + 8] = pa1.x;
        a32[(m0 + 1) * 20 + prow + 8] = pa1.y;
        a32[(m0 + 2) * 20 + prow + 8] = pa1.z;
        a32[(m0 + 3) * 20 + prow + 8] = pa1.w;
    }
    ASYNC_COPY16(Bptr,                  &Bs[0][tid * 8]);
    ASYNC_COPY16(Bptr + (size_t)64 * K, &Bs[0][64 * LDKB + tid * 8]);
    pa0 = *(const uint4*)(abase + (size_t)16 * PN);
    pa1 = *(const uint4*)(abase + (size_t)24 * PN);
    __syncthreads();

    int cur = 0;
    for (int kt = 0; kt < K; kt += 32) {
        if (kt + 32 < K) {
            u32* a32 = (u32*)&As[cur ^ 1][0];
            a32[(m0 + 0) * 20 + prow] = pa0.x;
            a32[(m0 + 1) * 20 + prow] = pa0.y;
            a32[(m0 + 2) * 20 + prow] = pa0.z;
            a32[(m0 + 3) * 20 + prow] = pa0.w;
            a32[(m0 + 0) * 20 + prow + 8] = pa1.x;
            a32[(m0 + 1) * 20 + prow + 8] = pa1.y;
            a32[(m0 + 2) * 20 + prow + 8] = pa1.z;
            a32[(m0 + 3) * 20 + prow + 8] = pa1.w;
            ASYNC_COPY16(Bptr + kt + 32,                  &Bs[cur ^ 1][tid * 8]);
            ASYNC_COPY16(Bptr + (size_t)64 * K + kt + 32, &Bs[cur ^ 1][64 * LDKB + tid * 8]);
            if (kt + 64 < K) {
                const u32* nxt = abase + (size_t)((kt >> 1) + 32) * PN;
                pa0 = *(const uint4*)(nxt);
                pa1 = *(const uint4*)(nxt + (size_t)8 * PN);
            }
        }
        bf16x8 af[4], bfr[4];
        #pragma unroll
        for (int i = 0; i < 4; i++) af[i]  = *(const bf16x8*)&As[cur][(wm + i * 16 + mrow) * LDKA + k0];
        #pragma unroll
        for (int j = 0; j < 4; j++) bfr[j] = *(const bf16x8*)&Bs[cur][(wn + j * 16 + mrow) * LDKB + k0];
        #pragma unroll
        for (int i = 0; i < 4; i++)
            #pragma unroll
            for (int j = 0; j < 4; j++)
                acc[i][j] = __builtin_amdgcn_mfma_f32_16x16x32_bf16(af[i], bfr[j], acc[i][j], 0, 0, 0);
        __syncthreads();
        cur ^= 1;
    }

    const int rq = (lane >> 4) << 2;
    #pragma unroll
    for (int i = 0; i < 4; i++) {
        #pragma unroll
        for (int rr = 0; rr < 4; rr++) {
            int row = tileM + wm + i * 16 + rq + rr;
            size_t base = (size_t)row * Nc + tileN + wn + mrow;
            #pragma unroll
            for (int j = 0; j < 4; j++) Cf[base + j * 16] = acc[i][j][rr];
        }
    }
}

// ------------------------------------------------- FFT conv + hadamard/scale epilogue
// Round-1 proven structure (177us): 512 threads, radix-2^2 per stage, 4 independent
// butterflies/thread/stage (ILP), XOR-swizzled LDS, hoisted/incremental twiddles.
__global__ __launch_bounds__(512) void fftconv(const u32* __restrict__ vt,
                                               const float* __restrict__ g_raw,
                                               const float* __restrict__ s_full,
                                               u32* __restrict__ yt) {
    __shared__ float2 Z[PN];   // 64 KB
    const int tid = threadIdx.x;           // 0..511
    const int row = blockIdx.x;            // b*512 + pair
    const int bh = row >> 5;
    const u32* vp = vt + (size_t)row * PN;

    #pragma unroll
    for (int it = 0; it < 2; it++) {
        int n0 = (tid + it * 512) * 8;
        uint4 u0 = *(const uint4*)(vp + n0);
        uint4 u1 = *(const uint4*)(vp + n0 + 4);
        u32 uu[8] = {u0.x, u0.y, u0.z, u0.w, u1.x, u1.y, u1.z, u1.w};
        #pragma unroll
        for (int m = 0; m < 8; m++) {
            bf16x2 p = *(bf16x2*)&uu[m];
            Z[PHYS(n0 + m)] = f2((float)p.x, (float)p.y);
        }
    }
    __syncthreads();

    // forward DIF: radix-4 stages s=11,9,7,5,3,1 then radix-2 s=0
    #pragma unroll
    for (int si = 0; si < 6; si++) {
        const int s = 11 - 2 * si;
        const int h = 1 << s;
        const float ang = -6.283185307179586f / (float)(4 * h);
        float sn, cs;
        __sincosf(ang * (float)(tid & (h - 1)), &sn, &cs);
        float2 w2 = f2(cs, sn);
        #pragma unroll
        for (int it = 0; it < 4; it++) {
            int q = tid + it * 512;
            int i = ((q >> s) << (s + 2)) + (q & (h - 1));
            float2 w1 = cmul(w2, w2);
            float2 a = Z[PHYS(i)],         bb = Z[PHYS(i + h)];
            float2 c = Z[PHYS(i + 2 * h)], d  = Z[PHYS(i + 3 * h)];
            float2 A0 = cadd(a, c);
            float2 C0 = cmul(csub(a, c), w2);
            float2 B0 = cadd(bb, d);
            float2 t  = cmul(csub(bb, d), w2);
            float2 D0 = f2(t.y, -t.x);               // * (-i)
            Z[PHYS(i)]         = cadd(A0, B0);
            Z[PHYS(i + h)]     = cmul(csub(A0, B0), w1);
            Z[PHYS(i + 2 * h)] = cadd(C0, D0);
            Z[PHYS(i + 3 * h)] = cmul(csub(C0, D0), w1);
            if (h == 2048) w2 = cmul(w2, f2(0.92387953251f, -0.38268343236f)); // cis(-pi/8)
        }
        __syncthreads();
    }
    #pragma unroll
    for (int it = 0; it < 8; it++) {               // radix-2 s=0, twiddle-free
        int i = 2 * (tid + it * 512);
        float2 u = Z[PHYS(i)], t = Z[PHYS(i + 1)];
        Z[PHYS(i)]     = cadd(u, t);
        Z[PHYS(i + 1)] = csub(u, t);
    }
    __syncthreads();

    // spectral stage in bitrev addressing
    const float* gr = g_raw + (size_t)bh * (2 * PN);
    const float* gi = gr + PN;
    for (int m = tid; m < PN / 2 + 1; m += 512) {
        int p  = (m < PN / 2) ? 2 * m : 1;
        int k  = __brev((unsigned)p) >> 19;
        int Nk = (PN - k) & (PN - 1);
        int qd = __brev((unsigned)Nk) >> 19;
        float2 Za = Z[PHYS(p)], Zb = Z[PHYS(qd)];
        float v1r = 0.5f * (Za.x + Zb.x), v1i = 0.5f * (Za.y - Zb.y);
        float v2r = 0.5f * (Za.y + Zb.y), v2i = 0.5f * (Zb.x - Za.x);
        float grk = gr[k],  gik = gi[k];
        float grn = gr[Nk], gin = gi[Nk];
        float y1r  = v1r * grk - v1i * gik, y1i  = v1r * gik + v1i * grk;
        float y2r  = v2r * grk - v2i * gik, y2i  = v2r * gik + v2i * grk;
        float y1nr = v1r * grn + v1i * gin, y1ni = v1r * gin - v1i * grn;
        float y2nr = v2r * grn + v2i * gin, y2ni = v2r * gin - v2i * grn;
        float ys1r = 0.5f * (y1r + y1nr), ys1i = 0.5f * (y1i - y1ni);
        float ys2r = 0.5f * (y2r + y2nr), ys2i = 0.5f * (y2i - y2ni);
        Z[PHYS(p)] = f2(ys1r - ys2i, ys1i + ys2r);
        if (qd != p) Z[PHYS(qd)] = f2(ys1r + ys2i, ys2r - ys1i);
    }
    __syncthreads();

    // inverse DIT: radix-4 stages s=0,2,4,6,8,10 then radix-2 s=12
    #pragma unroll
    for (int si = 0; si < 6; si++) {
        const int s = 2 * si;
        const int h = 1 << s;
        const float ang = 6.283185307179586f / (float)(4 * h);
        float sn, cs;
        __sincosf(ang * (float)(tid & (h - 1)), &sn, &cs);
        float2 w2a = f2(cs, sn);
        float2 w2b = (h == 1024) ? cmul(w2a, f2(0.70710678119f, 0.70710678119f)) : w2a;
        #pragma unroll
        for (int it = 0; it < 4; it++) {
            int q = tid + it * 512;
            int i = ((q >> s) << (s + 2)) + (q & (h - 1));
            float2 w2 = (it & 1) ? w2b : w2a;
            float2 w1 = cmul(w2, w2);
            float2 a = Z[PHYS(i)],         bb = Z[PHYS(i + h)];
            float2 c = Z[PHYS(i + 2 * h)], d  = Z[PHYS(i + 3 * h)];
            float2 tb = cmul(bb, w1);
            float2 p0 = cadd(a, tb), p1 = csub(a, tb);
            float2 td = cmul(d, w1);
            float2 q0 = cadd(c, td), q1 = csub(c, td);
            float2 wq0 = cmul(q0, w2);
            float2 e   = cmul(q1, w2);
            float2 ei  = f2(-e.y, e.x);              // * (+i)
            Z[PHYS(i)]         = cadd(p0, wq0);
            Z[PHYS(i + 2 * h)] = csub(p0, wq0);
            Z[PHYS(i + h)]     = cadd(p1, ei);
            Z[PHYS(i + 3 * h)] = csub(p1, ei);
        }
        __syncthreads();
    }
    {
        const float ang = 6.283185307179586f / (float)PN;
        float sn, cs;
        __sincosf(ang * (float)tid, &sn, &cs);
        float2 w = f2(cs, sn);
        #pragma unroll
        for (int it = 0; it < 8; it++) {           // radix-2 s=12, chained twiddle
            int q = tid + it * 512;
            float2 u = Z[PHYS(q)];
            float2 t = cmul(Z[PHYS(q + PN / 2)], w);
            Z[PHYS(q)]          = cadd(u, t);
            Z[PHYS(q + PN / 2)] = csub(u, t);
            w = cmul(w, f2(0.92387953251f, 0.38268343236f)); // cis(+pi/8)
        }
    }
    __syncthreads();

    // epilogue: v_tilde + second-butterfly(s * first-butterfly(v_tilde))
    const float* sp = s_full + (size_t)bh * PN;
    u32* yp = yt + (size_t)row * PN;
    const float inv = 1.0f / (float)PN;
    const float I2 = 0.70710678118654752440f;
    #pragma unroll
    for (int it = 0; it < 2; it++) {
        int nb = tid + it * 512;       // 0..1023
        int n0 = nb * 8;
        int np0 = nb * 4;
        u32 ou[8];
        #pragma unroll
        for (int pp = 0; pp < 4; pp++) {
            float2 z0 = Z[PHYS(n0 + 2 * pp)];
            float2 z1 = Z[PHYS(n0 + 2 * pp + 1)];
            float s0  = sp[np0 + pp];
            float s1v = sp[np0 + pp + PN / 2];
            float ax = z0.x * inv, ay = z0.y * inv;
            float bx = z1.x * inv, by = z1.y * inv;
            float wlx = (ax + bx) * I2 * s0, whx = (ax - bx) * I2 * s1v;
            float evx = (wlx + whx) * I2,   odx = (wlx - whx) * I2;
            float wly = (ay + by) * I2 * s0, why = (ay - by) * I2 * s1v;
            float evy = (wly + why) * I2,   ody = (wly - why) * I2;
            ou[2 * pp]     = packbf(ax + evx, ay + evy);
            ou[2 * pp + 1] = packbf(bx + odx, by + ody);
        }
        *(uint4*)(yp + n0)     = make_uint4(ou[0], ou[1], ou[2], ou[3]);
        *(uint4*)(yp + n0 + 4) = make_uint4(ou[4], ou[5], ou[6], ou[7]);
    }
}

// ================================================================ launcher
extern "C" void kernel_launch(void* const* d_in, const int* in_sizes, int n_in,
                              void* d_out, int out_size, void* d_ws, size_t ws_size,
                              hipStream_t stream) {
    const float* x    = (const float*)d_in[0];
    const float* w_q  = (const float*)d_in[1];
    const float* w_v  = (const float*)d_in[2];
    const float* w_o  = (const float*)d_in[3];
    const float* ln_g = (const float*)d_in[4];
    const float* ln_b = (const float*)d_in[5];
    const float* gw1  = (const float*)d_in[6];
    const float* gw2  = (const float*)d_in[7];
    const float* ww1  = (const float*)d_in[8];
    const float* ww2  = (const float*)d_in[9];
    float* out = (float*)d_out;

    const size_t XE = (size_t)PB * PN * PD;        // 33554432
    __bf16* xb   = (__bf16*)d_ws;                  // x bf16; later reused: fft out (pair)
    __bf16* vb   = xb + XE;                        // gemm1 out (pair layout)
    __bf16* wvt  = vb + XE;
    __bf16* wot  = wvt + (size_t)PD * PD;
    float*  xsum = (float*)(wot + (size_t)PD * PD);
    float*  bar  = xsum + PB * PD;
    float*  tg   = bar + PB * PD;
    float*  tw   = tg + 64 * PGH;
    float*  graw = tw + 64 * PGH;
    float*  sful = graw + (size_t)64 * 2 * PN;

    hipMemsetAsync(xsum, 0, PB * PD * sizeof(float), stream);

    convert_reduce<<<dim3(PN / 128, 1, PB), 256, 0, stream>>>(x, xb, xsum);
    transpose_w<<<dim3(16, 16, 2), 256, 0, stream>>>(w_v, w_o, wvt, wot);
    barq_ln<<<dim3(PD / 64, PB), 256, 0, stream>>>(xsum, w_q, ln_g, ln_b, bar);
    small1<<<PB * PH, 256, 0, stream>>>(bar, gw1, ww1, tg, tw);
    small2<<<dim3(96, 8), 256, 0, stream>>>(tg, tw, gw2, ww2, graw, sful);
    // v = x @ w_v, written directly in pair-transposed layout
    gemm_pair<<<dim3(PD / 128, PB * PN / 128), 256, 0, stream>>>(xb, wvt, (u32*)vb);
    // FFT conv: vb (pair) -> xb (pair)
    fftconv<<<PB * 512, 512, 0, stream>>>((const u32*)vb, graw, sful, (u32*)xb);
    // out = y @ w_o, A staged from pair layout
    gemm_ta<<<dim3(PD / 128, PB * PN / 128), 256, 0, stream>>>((const u32*)xb, wot, out);
}